// Round 1
// baseline (1309.912 us; speedup 1.0000x reference)
//
#include <hip/hip_runtime.h>

typedef unsigned short u16;
typedef __attribute__((ext_vector_type(8))) short s16x8;
typedef __attribute__((ext_vector_type(4))) float f32x4;

#define R3 32768
#define NPTS 16384

__device__ __forceinline__ float b2f(u16 u) {
  union { unsigned int i; float f; } v; v.i = ((unsigned int)u) << 16; return v.f;
}
__device__ __forceinline__ u16 f2b(float f) {
  union { float f; unsigned int i; } v; v.f = f;
  unsigned int x = v.i;
  return (u16)((x + 0x7fffu + ((x >> 16) & 1u)) >> 16);
}
__device__ __forceinline__ void split2(float x, u16& h, u16& l) {
  h = f2b(x); l = f2b(x - b2f(h));
}
__device__ __forceinline__ float silu(float x) {
  return x / (1.f + __expf(-x));
}
// async 16B global->LDS (linear dest: wave-uniform base + lane*16)
__device__ __forceinline__ void gload16(const u16* g, char* l) {
  __builtin_amdgcn_global_load_lds(
      (const __attribute__((address_space(1))) unsigned int*)g,
      (__attribute__((address_space(3))) unsigned int*)l, 16, 0, 0);
}

// ---- K0: weights -> hi/lo bf16. conv: [tap][co][ci]; mlp: [co][ci] --------
__global__ void convert_weights(const float* __restrict__ w1, const float* __restrict__ w2,
                                const float* __restrict__ wm,
                                u16* __restrict__ Wh1, u16* __restrict__ Wl1,
                                u16* __restrict__ Wh2, u16* __restrict__ Wl2,
                                u16* __restrict__ Whm, u16* __restrict__ Wlm) {
  int e = blockIdx.x * 256 + threadIdx.x;
  if (e < 27 * 128 * 64) {
    int t = e / (128 * 64), co = (e / 64) % 128, ci = e % 64;
    split2(w1[(co * 64 + ci) * 27 + t], Wh1[e], Wl1[e]);
  }
  if (e < 27 * 128 * 128) {
    int t = e / (128 * 128), co = (e / 128) % 128, ci = e % 128;
    split2(w2[(co * 128 + ci) * 27 + t], Wh2[e], Wl2[e]);
  }
  if (e < 128 * 64) split2(wm[e], Whm[e], Wlm[e]);
}

// ---- K_pvox (proven) ------------------------------------------------------
__global__ void calc_pvox(const float* __restrict__ coords, int* __restrict__ pvox) {
  int t = blockIdx.x * 256 + threadIdx.x;  // < 4*16384
  if (t >= 4 * NPTS) return;
  const float* cp = coords + (size_t)t * 3;
  int ix = min(max((int)floorf(cp[0] * 32.f), 0), 31);
  int iy = min(max((int)floorf(cp[1] * 32.f), 0), 31);
  int iz = min(max((int)floorf(cp[2] * 32.f), 0), 31);
  pvox[t] = (ix * 32 + iy) * 32 + iz;
}

// ---- K_scatter (proven) ---------------------------------------------------
__global__ void __launch_bounds__(256)
scatter_feats(const float* __restrict__ features, const int* __restrict__ pvox,
              float* __restrict__ Gsum, float* __restrict__ Gcnt) {
  size_t t = (size_t)blockIdx.x * 256 + threadIdx.x;  // < 4 * 2^20
  int n  = (int)(t & 16383);
  int ci = (int)((t >> 14) & 63);
  int bi = (int)(t >> 20);
  int v = pvox[bi * NPTS + n];
  float val = features[t];  // features flat [b][ci][n] index == t
  atomicAdd(&Gsum[((size_t)bi * R3 + v) * 64 + ci], val);
  if (ci == 0) atomicAdd(&Gcnt[bi * R3 + v], 1.f);
}

// ---- K_finalize: X1p[padded 34^3] = bf16(Gsum / max(cnt,1)) ---------------
__global__ void __launch_bounds__(256)
finalize_grid(const float* __restrict__ Gsum, const float* __restrict__ Gcnt,
              u16* __restrict__ X1p) {
  size_t t = (size_t)blockIdx.x * 256 + threadIdx.x;  // < 4*32768*64
  float c = Gcnt[t >> 6];
  float v = Gsum[t] / fmaxf(c, 1.f);
  int ci = (int)(t & 63);
  int vox = (int)(t >> 6) & 32767;
  int bi = (int)(t >> 21);
  int vx = vox >> 10, vy = (vox >> 5) & 31, vz = vox & 31;
  size_t po = ((((size_t)bi * 34 + vx + 1) * 34 + vy + 1) * 34 + (vz + 1)) * 64 + ci;
  X1p[po] = f2b(v);
}

// ---- conv: padded X [b][34][34][34][CIN] bf16, W split hi/lo [tap][co][ci].
// Double-buffered global_load_lds staging (stage for g+1 interleaved inside
// compute of g, raw s_barrier + one vmcnt(0)/g); XOR chunk swizzle (c^=r&7)
// for conflict-free ds_read_b128; weight+B register prefetch 1 step ahead.
// 2-term split MFMA + calibrated C/D decode (PROVEN r8/r9).
template<int CIN, bool PADOUT>
__global__ void __launch_bounds__(256, 2)
conv_mfma_async(const u16* __restrict__ Xp, const u16* __restrict__ Wh,
                const u16* __restrict__ Wl, const float* __restrict__ bias,
                const float* __restrict__ gamma, const float* __restrict__ beta,
                u16* __restrict__ Yb) {
  constexpr int CPR  = CIN / 8;            // 16B chunks per row
  constexpr int KS   = CIN / 32;
  constexpr int M    = 3 * KS;             // kb-steps per tap-group g
  constexpr int TOTI = 136 * CPR / 64;     // stage instrs per tile: 17 / 34
  constexpr int SJ   = (TOTI + 3) / 4;     // max per wave: 5 / 9
  constexpr int BUFB = 136 * CIN * 2;      // bytes per LDS buffer
  constexpr int SBYTES = 4 * 2 * 32 * 33 * 4;
  constexpr int LBYTES = (2 * BUFB > SBYTES) ? 2 * BUFB : SBYTES;
  __shared__ __align__(16) char ldsbuf[LBYTES];
  float* ldsW = (float*)ldsbuf;

  const int tid = threadIdx.x;
  const int wave = tid >> 6, lane = tid & 63;
  const int l15 = lane & 15, q = lane >> 4;
  const int cobase = wave * 32;
  const int bi = blockIdx.x >> 8;
  const int rem = blockIdx.x & 255;
  const int x = rem >> 3, y0 = (rem & 7) << 2;

  u16* b0 = (u16*)ldsbuf;
  u16* b1 = (u16*)(ldsbuf + BUFB);

  // per-thread stage source sub-offsets (u16 units inside one (dx,dy) slab):
  // LDS chunk e=(k<<6)+lane holds source chunk (r, c ^ (r&7)), r=e/CPR, c=e%CPR
  int soff[M];
#pragma unroll
  for (int j = 0; j < M; ++j) {
    int e = (((j << 2) + wave) << 6) + lane;
    int r = e / CPR, c = e & (CPR - 1);
    soff[j] = r * CIN + ((c ^ (r & 7)) << 3);
  }

  // ---- issue stage for g=0 (dx=dy=-1 -> px=x, slab-y=y0) ----
  {
    const int ab0 = (((bi * 34 + x) * 34) + y0) * (34 * CIN);
#pragma unroll
    for (int j = 0; j < SJ; ++j)
      if ((j << 2) + wave < TOTI)
        gload16(Xp + ab0 + soff[j], (char*)b0 + ((((j << 2) + wave)) << 10));
  }

  // ---- runtime C/D calibration (PROVEN r8) ----
  u16 oneb = f2b(1.0f), lidb = f2b((float)(l15 + 1));
  s16x8 vone, vlid;
#pragma unroll
  for (int e = 0; e < 8; ++e) { vone[e] = (short)oneb; vlid[e] = (short)lidb; }
  f32x4 z4 = {0.f, 0.f, 0.f, 0.f};
  f32x4 d1 = __builtin_amdgcn_mfma_f32_16x16x32_bf16(vlid, vone, z4, 0, 0, 0);
  f32x4 d2 = __builtin_amdgcn_mfma_f32_16x16x32_bf16(vone, vlid, z4, 0, 0, 0);
  int mdec[4], ndec[4];
#pragma unroll
  for (int r = 0; r < 4; ++r) {
    mdec[r] = (int)(d1[r] * 0.03125f + 0.5f) - 1;
    ndec[r] = (int)(d2[r] * 0.03125f + 0.5f) - 1;
  }

  f32x4 acc[2][2][4];  // [ct][vt][line]
#pragma unroll
  for (int a = 0; a < 2; ++a)
#pragma unroll
    for (int b = 0; b < 2; ++b)
#pragma unroll
      for (int c = 0; c < 4; ++c) acc[a][b][c] = (f32x4){0.f, 0.f, 0.f, 0.f};

  s16x8 ah[2][2], al[2][2], bbv[2][2][4];

#define LOADW(T, KB, DST) do {                                                \
    const int ko_ = (KB) * 32 + q * 8;                                        \
    _Pragma("unroll")                                                         \
    for (int ct = 0; ct < 2; ++ct) {                                          \
      size_t wo_ = ((size_t)((T) * 128 + cobase + ct * 16 + l15)) * CIN + ko_;\
      ah[DST][ct] = *(const s16x8*)(Wh + wo_);                                \
      al[DST][ct] = *(const s16x8*)(Wl + wo_);                                \
    } } while (0)

#define LOADB(MM, DST) do {                                                   \
    const int dz_ = (MM) / KS, kb_ = (MM) % KS;                               \
    _Pragma("unroll")                                                         \
    for (int vt = 0; vt < 2; ++vt)                                            \
      _Pragma("unroll")                                                       \
      for (int ln = 0; ln < 4; ++ln) {                                        \
        int rr_ = ln * 34 + vt * 16 + l15 + dz_;                              \
        bbv[DST][vt][ln] = *(const s16x8*)(bcur + rr_ * CIN +                 \
                            (((kb_ * 4 + q) ^ (rr_ & 7)) << 3));              \
      } } while (0)

  u16* bcur = b0; u16* bnxt = b1;
  LOADW(0, 0, 0);  // weights for (g=0, m=0)

  asm volatile("s_waitcnt vmcnt(0)" ::: "memory");
  __builtin_amdgcn_s_barrier();
  asm volatile("" ::: "memory");

  for (int g = 0; g < 9; ++g) {
    const bool hn = (g < 8);
    const int gg = g + 1;
    // next slab base: px = x + gg/3, slab-y = y0 + gg%3 (dx,dy = gg/3-1, gg%3-1)
    const int abn = hn ? ((((bi * 34 + x + gg / 3) * 34) + (y0 + gg % 3)) * (34 * CIN)) : 0;
    LOADB(0, 0);
#pragma unroll
    for (int m = 0; m < M; ++m) {
      const int pm = m & 1, nm = pm ^ 1;
      // weight prefetch for m+1 (or next g's m=0) -- BEFORE stage issue, so
      // the compiler's in-order vmcnt wait for these never drains the stage q
      if (m + 1 < M)      LOADW(g * 3 + (m + 1) / KS, (m + 1) % KS, nm);
      else if (hn)        LOADW(gg * 3, 0, nm);
      // one async stage instruction for tile g+1
      if (hn && (m << 2) + wave < TOTI)
        gload16(Xp + abn + soff[m], (char*)bnxt + (((m << 2) + wave) << 10));
      // B-fragment prefetch for m+1
      if (m + 1 < M)      LOADB(m + 1, nm);
      // MFMA cluster
      __builtin_amdgcn_s_setprio(1);
#pragma unroll
      for (int ct = 0; ct < 2; ++ct)
#pragma unroll
        for (int vt = 0; vt < 2; ++vt)
#pragma unroll
          for (int ln = 0; ln < 4; ++ln) {
            acc[ct][vt][ln] = __builtin_amdgcn_mfma_f32_16x16x32_bf16(
                ah[pm][ct], bbv[pm][vt][ln], acc[ct][vt][ln], 0, 0, 0);
            acc[ct][vt][ln] = __builtin_amdgcn_mfma_f32_16x16x32_bf16(
                al[pm][ct], bbv[pm][vt][ln], acc[ct][vt][ln], 0, 0, 0);
          }
      __builtin_amdgcn_s_setprio(0);
    }
    asm volatile("s_waitcnt vmcnt(0)" ::: "memory");
    __builtin_amdgcn_s_barrier();
    asm volatile("" ::: "memory");
    u16* tb = bcur; bcur = bnxt; bnxt = tb;
  }
#undef LOADW
#undef LOADB

  // ---- epilogue: decoded scatter through LDS, 2 lines per pass ------------
  const int half = lane >> 5, zl = lane & 31;
  for (int p = 0; p < 2; ++p) {
    __syncthreads();   // drains buffer reads -> safe to overwrite
#pragma unroll
    for (int l2 = 0; l2 < 2; ++l2)
#pragma unroll
      for (int ct = 0; ct < 2; ++ct)
#pragma unroll
        for (int vt = 0; vt < 2; ++vt)
#pragma unroll
          for (int r = 0; r < 4; ++r)
            ldsW[((wave * 2 + l2) * 32 + ct * 16 + mdec[r]) * 33 + vt * 16 + ndec[r]] =
                acc[ct][vt][2 * p + l2][r];
    __syncthreads();
    const int co0 = cobase + half * 16;
#pragma unroll
    for (int l2 = 0; l2 < 2; ++l2) {
      float v[16];
#pragma unroll
      for (int j = 0; j < 16; ++j)
        v[j] = ldsW[((wave * 2 + l2) * 32 + half * 16 + j) * 33 + zl] + bias[co0 + j];
      float mu = 0.f;
#pragma unroll
      for (int j = 0; j < 16; ++j) mu += v[j];
      mu *= 0.0625f;
      float var = 0.f;
#pragma unroll
      for (int j = 0; j < 16; ++j) { float d = v[j] - mu; var = fmaf(d, d, var); }
      var *= 0.0625f;
      float rs = rsqrtf(var + 1e-5f);
#pragma unroll
      for (int j = 0; j < 16; ++j) {
        float xn = (v[j] - mu) * rs * gamma[co0 + j] + beta[co0 + j];
        v[j] = silu(xn);
      }
      size_t row;
      if (PADOUT)
        row = (((size_t)bi * 34 + x + 1) * 34 + (y0 + 2 * p + l2 + 1)) * 34 + (zl + 1);
      else
        row = (size_t)bi * R3 + (size_t)((x * 32 + y0 + 2 * p + l2) * 32 + zl);
      u16 outv[16];
#pragma unroll
      for (int j = 0; j < 16; ++j) outv[j] = f2b(v[j]);
      u16* yp = Yb + row * 128 + co0;
      *(uint4*)(yp)     = *(uint4*)(outv);
      *(uint4*)(yp + 8) = *(uint4*)(outv + 8);
    }
  }
}

// ---- K_mlp: MFMA 1x1 conv + fused global-GN stats -------------------------
__global__ void __launch_bounds__(256)
mlp_mfma(const float* __restrict__ features, const u16* __restrict__ Whm,
         const u16* __restrict__ Wlm, const float* __restrict__ mb,
         u16* __restrict__ pf, float* __restrict__ stats) {
  constexpr int XBYTES = 64 * 72 * 2;
  constexpr int SBYTES = 4 * 64 * 33 * 4;   // 4 waves x [64pt][32co+1]
  __shared__ __align__(16) char ldsbuf[(XBYTES > SBYTES) ? XBYTES : SBYTES];
  u16* Xs = (u16*)ldsbuf;
  float* ldsW = (float*)ldsbuf;

  const int tid = threadIdx.x;
  const int wave = tid >> 6, lane = tid & 63;
  const int l15 = lane & 15, q = lane >> 4;
  const int cobase = wave * 32;
  const int bi = blockIdx.x >> 8;
  const int n0 = (blockIdx.x & 255) << 6;

  // calibration (PROVEN r8)
  u16 oneb = f2b(1.0f), lidb = f2b((float)(l15 + 1));
  s16x8 vone, vlid;
#pragma unroll
  for (int e = 0; e < 8; ++e) { vone[e] = (short)oneb; vlid[e] = (short)lidb; }
  f32x4 z4 = {0.f, 0.f, 0.f, 0.f};
  f32x4 d1 = __builtin_amdgcn_mfma_f32_16x16x32_bf16(vlid, vone, z4, 0, 0, 0);
  f32x4 d2 = __builtin_amdgcn_mfma_f32_16x16x32_bf16(vone, vlid, z4, 0, 0, 0);
  int mdec[4], ndec[4];
#pragma unroll
  for (int r = 0; r < 4; ++r) {
    mdec[r] = (int)(d1[r] * 0.03125f + 0.5f) - 1;
    ndec[r] = (int)(d2[r] * 0.03125f + 0.5f) - 1;
  }

  // stage transpose: Xs[pt][ci]
  for (int e = tid; e < 4096; e += 256) {
    int ci = e >> 6, nn = e & 63;
    Xs[nn * 72 + ci] = f2b(features[((size_t)bi * 64 + ci) * NPTS + n0 + nn]);
  }
  __syncthreads();

  f32x4 acc[2][4];  // [ct][vt: 4 point-tiles of 16]
#pragma unroll
  for (int a = 0; a < 2; ++a)
#pragma unroll
    for (int b = 0; b < 4; ++b) acc[a][b] = (f32x4){0.f, 0.f, 0.f, 0.f};

#pragma unroll
  for (int kb = 0; kb < 2; ++kb) {
    const int ko = kb * 32 + q * 8;
    s16x8 ah[2], al[2], bb[4];
#pragma unroll
    for (int ct = 0; ct < 2; ++ct) {
      size_t wo = ((size_t)(cobase + ct * 16 + l15)) * 64 + ko;
      ah[ct] = *(const s16x8*)(Whm + wo);
      al[ct] = *(const s16x8*)(Wlm + wo);
    }
#pragma unroll
    for (int vt = 0; vt < 4; ++vt)
      bb[vt] = *(const s16x8*)(&Xs[(vt * 16 + l15) * 72 + ko]);
#pragma unroll
    for (int ct = 0; ct < 2; ++ct)
#pragma unroll
      for (int vt = 0; vt < 4; ++vt) {
        acc[ct][vt] = __builtin_amdgcn_mfma_f32_16x16x32_bf16(ah[ct], bb[vt], acc[ct][vt], 0, 0, 0);
        acc[ct][vt] = __builtin_amdgcn_mfma_f32_16x16x32_bf16(al[ct], bb[vt], acc[ct][vt], 0, 0, 0);
      }
  }

  // epilogue: decoded scatter -> ldsW[wave][pt][co32], then store + stats
  __syncthreads();
#pragma unroll
  for (int ct = 0; ct < 2; ++ct)
#pragma unroll
    for (int vt = 0; vt < 4; ++vt)
#pragma unroll
      for (int r = 0; r < 4; ++r)
        ldsW[(wave * 64 + vt * 16 + ndec[r]) * 33 + ct * 16 + mdec[r]] = acc[ct][vt][r];
  __syncthreads();

  float v[32];
  float s0 = 0.f, q0 = 0.f, s1 = 0.f, q1 = 0.f;
#pragma unroll
  for (int j = 0; j < 32; ++j) {
    v[j] = ldsW[(wave * 64 + lane) * 33 + j] + mb[cobase + j];
    if (j < 16) { s0 += v[j]; q0 = fmaf(v[j], v[j], q0); }
    else        { s1 += v[j]; q1 = fmaf(v[j], v[j], q1); }
  }
  u16 outv[32];
#pragma unroll
  for (int j = 0; j < 32; ++j) outv[j] = f2b(v[j]);
  u16* yp = pf + ((size_t)bi * NPTS + n0 + lane) * 128 + cobase;
#pragma unroll
  for (int k = 0; k < 4; ++k) *(uint4*)(yp + 8 * k) = *(uint4*)(outv + 8 * k);

#pragma unroll
  for (int off = 32; off > 0; off >>= 1) {
    s0 += __shfl_xor(s0, off); q0 += __shfl_xor(q0, off);
    s1 += __shfl_xor(s1, off); q1 += __shfl_xor(q1, off);
  }
  if (lane == 0) {
    atomicAdd(&stats[(bi * 8 + 2 * wave + 0) * 2 + 0], s0);
    atomicAdd(&stats[(bi * 8 + 2 * wave + 0) * 2 + 1], q0);
    atomicAdd(&stats[(bi * 8 + 2 * wave + 1) * 2 + 0], s1);
    atomicAdd(&stats[(bi * 8 + 2 * wave + 1) * 2 + 1], q1);
  }
}

// ---- K_final (proven) -----------------------------------------------------
__global__ void __launch_bounds__(256)
final_fuse(const float* __restrict__ coords, const u16* __restrict__ H,
           const u16* __restrict__ pf, const float* __restrict__ stats,
           const float* __restrict__ gg, const float* __restrict__ gb,
           float* __restrict__ out) {
  __shared__ float trans[64][130];
  const int tid = threadIdx.x;
  const int wave = tid >> 6, lane = tid & 63;
  const int bi = blockIdx.x >> 8;
  const int p0 = (blockIdx.x & 255) << 6;
  const int co = lane * 2;
  const int grp = co >> 4;
  const float cntInv = 1.f / (16.f * 16384.f);
  float S  = stats[(bi * 8 + grp) * 2 + 0];
  float SS = stats[(bi * 8 + grp) * 2 + 1];
  float mu = S * cntInv;
  float var = SS * cntInv - mu * mu;
  float rs = rsqrtf(var + 1e-5f);
  float g0 = gg[co], g1 = gg[co + 1], b0 = gb[co], b1 = gb[co + 1];

  for (int pi = 0; pi < 16; ++pi) {
    int pl = wave * 16 + pi;
    int p = p0 + pl;
    const float* cp = coords + ((size_t)bi * NPTS + p) * 3;
    float cx = cp[0] * 32.f, cy = cp[1] * 32.f, cz = cp[2] * 32.f;
    float fx = floorf(cx), fy = floorf(cy), fz = floorf(cz);
    int ix = min(max((int)fx, 0), 31);
    int iy = min(max((int)fy, 0), 31);
    int iz = min(max((int)fz, 0), 31);
    float rx = cx - fx, ry = cy - fy, rz = cz - fz;
    int hx = min(ix + 1, 31), hy = min(iy + 1, 31), hz = min(iz + 1, 31);
    float a0 = 0.f, a1 = 0.f;
#pragma unroll
    for (int k = 0; k < 8; ++k) {
      int xb = k >> 2, yb = (k >> 1) & 1, zb = k & 1;
      float w = (xb ? rx : 1.f - rx) * (yb ? ry : 1.f - ry) * (zb ? rz : 1.f - rz);
      int vi = ((xb ? hx : ix) * 32 + (yb ? hy : iy)) * 32 + (zb ? hz : iz);
      unsigned hv = *(const unsigned*)(H + ((size_t)bi * R3 + vi) * 128 + co);
      a0 += w * b2f((u16)(hv & 0xffff));
      a1 += w * b2f((u16)(hv >> 16));
    }
    unsigned pv = *(const unsigned*)(pf + ((size_t)bi * NPTS + p) * 128 + co);
    float q0 = (b2f((u16)(pv & 0xffff)) - mu) * rs * g0 + b0;
    float q1 = (b2f((u16)(pv >> 16)) - mu) * rs * g1 + b1;
    trans[pl][co]     = silu(q0) + a0;
    trans[pl][co + 1] = silu(q1) + a1;
  }
  __syncthreads();
  for (int e = tid; e < 8192; e += 256) {
    int c = e >> 6, pp = e & 63;
    out[((size_t)bi * 128 + c) * NPTS + p0 + pp] = trans[pp][c];
  }
}

// ---- host -----------------------------------------------------------------
extern "C" void kernel_launch(void* const* d_in, const int* in_sizes, int n_in,
                              void* d_out, int out_size, void* d_ws, size_t ws_size,
                              hipStream_t stream) {
  const float* coords   = (const float*)d_in[0];
  const float* features = (const float*)d_in[1];
  const float* conv1_w  = (const float*)d_in[2];
  const float* conv1_b  = (const float*)d_in[3];
  const float* gn1_g    = (const float*)d_in[4];
  const float* gn1_b    = (const float*)d_in[5];
  const float* conv2_w  = (const float*)d_in[6];
  const float* conv2_b  = (const float*)d_in[7];
  const float* gn2_g    = (const float*)d_in[8];
  const float* gn2_b    = (const float*)d_in[9];
  const float* mlp_w    = (const float*)d_in[10];
  const float* mlp_b    = (const float*)d_in[11];
  const float* gnp_g    = (const float*)d_in[12];
  const float* gnp_b    = (const float*)d_in[13];

  char* ws = (char*)d_ws;
  // layout (bytes), total ~97.4 MB:
  float* Gsum = (float*)(ws + 0);            // 33,554,432 fp32 [b][vox][64]
  u16*   H    = (u16*)(ws + 0);              // alias: bf16 [b][vox][128] (Gsum dead)
  u16*   X1p  = (u16*)(ws + 33554432);       // 20,123,648 bf16 [b][34][34][34][64]
  u16*   pf   = (u16*)(ws + 33554432);       // alias X1p (written after conv1)
  u16*   X2p  = (u16*)(ws + 53678080);       // 40,247,296 bf16 [b][34][34][34][128]
  float* Gcnt = (float*)(ws + 93925376);     // 524,288
  float* stats= (float*)(ws + 94449664);     // 4,096
  int*   pvox = (int*)(ws + 94453760);       // 262,144
  u16*   Wh1  = (u16*)(ws + 94715904);       // 442,368
  u16*   Wl1  = (u16*)(ws + 95158272);       // 442,368
  u16*   Wh2  = (u16*)(ws + 95600640);       // 884,736
  u16*   Wl2  = (u16*)(ws + 96485376);       // 884,736
  u16*   Whm  = (u16*)(ws + 97370112);       // 16,384
  u16*   Wlm  = (u16*)(ws + 97386496);       // 16,384 -> 97,402,880

  hipMemsetAsync(ws, 0, 33554432, stream);                   // Gsum
  hipMemsetAsync(ws + 33554432, 0, 60370944, stream);        // X1p+X2p (zero halo)
  hipMemsetAsync(ws + 93925376, 0, 528384, stream);          // Gcnt + stats

  convert_weights<<<(27 * 128 * 128 + 255) / 256, 256, 0, stream>>>(
      conv1_w, conv2_w, mlp_w, Wh1, Wl1, Wh2, Wl2, Whm, Wlm);
  calc_pvox<<<(4 * NPTS + 255) / 256, 256, 0, stream>>>(coords, pvox);
  scatter_feats<<<16384, 256, 0, stream>>>(features, pvox, Gsum, Gcnt);
  finalize_grid<<<32768, 256, 0, stream>>>(Gsum, Gcnt, X1p);
  conv_mfma_async<64, true><<<1024, 256, 0, stream>>>(
      X1p, Wh1, Wl1, conv1_b, gn1_g, gn1_b, X2p);
  mlp_mfma<<<1024, 256, 0, stream>>>(features, Whm, Wlm, mlp_b, pf, stats);
  conv_mfma_async<128, false><<<1024, 256, 0, stream>>>(
      X2p, Wh2, Wl2, conv2_b, gn2_g, gn2_b, H);
  final_fuse<<<1024, 256, 0, stream>>>(coords, H, pf, stats, gnp_g, gnp_b,
                                       (float*)d_out);
}

// Round 2
// 929.316 us; speedup vs baseline: 1.4095x; 1.4095x over previous
//
#include <hip/hip_runtime.h>

typedef unsigned short u16;
typedef __attribute__((ext_vector_type(8))) short s16x8;
typedef __attribute__((ext_vector_type(4))) float f32x4;

#define R3 32768
#define NPTS 16384

__device__ __forceinline__ float b2f(u16 u) {
  union { unsigned int i; float f; } v; v.i = ((unsigned int)u) << 16; return v.f;
}
__device__ __forceinline__ u16 f2b(float f) {
  union { float f; unsigned int i; } v; v.f = f;
  unsigned int x = v.i;
  return (u16)((x + 0x7fffu + ((x >> 16) & 1u)) >> 16);
}
__device__ __forceinline__ void split2(float x, u16& h, u16& l) {
  h = f2b(x); l = f2b(x - b2f(h));
}
__device__ __forceinline__ float silu(float x) {
  return x / (1.f + __expf(-x));
}

// ---- K0: weights -> hi/lo bf16. conv: [tap][co][ci]; mlp: [co][ci] --------
__global__ void convert_weights(const float* __restrict__ w1, const float* __restrict__ w2,
                                const float* __restrict__ wm,
                                u16* __restrict__ Wh1, u16* __restrict__ Wl1,
                                u16* __restrict__ Wh2, u16* __restrict__ Wl2,
                                u16* __restrict__ Whm, u16* __restrict__ Wlm) {
  int e = blockIdx.x * 256 + threadIdx.x;
  if (e < 27 * 128 * 64) {
    int t = e / (128 * 64), co = (e / 64) % 128, ci = e % 64;
    split2(w1[(co * 64 + ci) * 27 + t], Wh1[e], Wl1[e]);
  }
  if (e < 27 * 128 * 128) {
    int t = e / (128 * 128), co = (e / 128) % 128, ci = e % 128;
    split2(w2[(co * 128 + ci) * 27 + t], Wh2[e], Wl2[e]);
  }
  if (e < 128 * 64) split2(wm[e], Whm[e], Wlm[e]);
}

// ---- K_pvox (proven) ------------------------------------------------------
__global__ void calc_pvox(const float* __restrict__ coords, int* __restrict__ pvox) {
  int t = blockIdx.x * 256 + threadIdx.x;  // < 4*16384
  if (t >= 4 * NPTS) return;
  const float* cp = coords + (size_t)t * 3;
  int ix = min(max((int)floorf(cp[0] * 32.f), 0), 31);
  int iy = min(max((int)floorf(cp[1] * 32.f), 0), 31);
  int iz = min(max((int)floorf(cp[2] * 32.f), 0), 31);
  pvox[t] = (ix * 32 + iy) * 32 + iz;
}

// ---- K_scatter (proven) ---------------------------------------------------
__global__ void __launch_bounds__(256)
scatter_feats(const float* __restrict__ features, const int* __restrict__ pvox,
              float* __restrict__ Gsum, float* __restrict__ Gcnt) {
  size_t t = (size_t)blockIdx.x * 256 + threadIdx.x;  // < 4 * 2^20
  int n  = (int)(t & 16383);
  int ci = (int)((t >> 14) & 63);
  int bi = (int)(t >> 20);
  int v = pvox[bi * NPTS + n];
  float val = features[t];  // features flat [b][ci][n] index == t
  atomicAdd(&Gsum[((size_t)bi * R3 + v) * 64 + ci], val);
  if (ci == 0) atomicAdd(&Gcnt[bi * R3 + v], 1.f);
}

// ---- K_finalize: X1p[padded 34^3] = bf16(Gsum / max(cnt,1)) ---------------
__global__ void __launch_bounds__(256)
finalize_grid(const float* __restrict__ Gsum, const float* __restrict__ Gcnt,
              u16* __restrict__ X1p) {
  size_t t = (size_t)blockIdx.x * 256 + threadIdx.x;  // < 4*32768*64
  float c = Gcnt[t >> 6];
  float v = Gsum[t] / fmaxf(c, 1.f);
  int ci = (int)(t & 63);
  int vox = (int)(t >> 6) & 32767;
  int bi = (int)(t >> 21);
  int vx = vox >> 10, vy = (vox >> 5) & 31, vz = vox & 31;
  size_t po = ((((size_t)bi * 34 + vx + 1) * 34 + vy + 1) * 34 + (vz + 1)) * 64 + ci;
  X1p[po] = f2b(v);
}

// ---- conv: PADDED X [b][34][34][34][CIN] bf16 (halo pre-zeroed), W split
// hi/lo bf16 [tap][co][ci]. r0-proven synchronous staging structure, but:
//  (a) staging is a pure contiguous uint4 copy (no bounds checks -> less
//      VALU, fewer live registers),
//  (b) __launch_bounds__(256,3): cap arch VGPR so VGPR+64 AGPR <= 168
//      -> 3 waves/SIMD -> 3 blocks/CU resident (r0 was 2, reg-limited).
// 2-term split MFMA + calibrated C/D decode (PROVEN r8/r9).
template<int CIN, bool PADOUT>
__global__ void __launch_bounds__(256, 3)
conv_mfma16p(const u16* __restrict__ Xp, const u16* __restrict__ Wh,
             const u16* __restrict__ Wl, const float* __restrict__ bias,
             const float* __restrict__ gamma, const float* __restrict__ beta,
             u16* __restrict__ Yb) {
  constexpr int CINP = CIN + 8;            // LDS row stride (odd x 16B)
  constexpr int ROWS = 136;                // 4 y-lines x 34 z (z' = -1..32)
  constexpr int CH8 = CIN / 8;
  constexpr int KS = CIN / 32;
  constexpr int XBYTES = ROWS * CINP * 2;
  constexpr int SBYTES = 4 * 2 * 32 * 33 * 4;   // 4 waves x 2 lines x [32co][33z]
  __shared__ __align__(16) char ldsbuf[(XBYTES > SBYTES) ? XBYTES : SBYTES];
  u16* Xs = (u16*)ldsbuf;
  float* ldsW = (float*)ldsbuf;            // valid only after X reads drained

  const int tid = threadIdx.x;
  const int wave = tid >> 6, lane = tid & 63;
  const int l15 = lane & 15, q = lane >> 4;
  const int cobase = wave * 32;

  const int bi = blockIdx.x >> 8;
  const int rem = blockIdx.x & 255;
  const int x = rem >> 3, y0 = (rem & 7) << 2;

  // ---- runtime C/D calibration (PROVEN r8) ----
  u16 oneb = f2b(1.0f), lidb = f2b((float)(l15 + 1));
  s16x8 vone, vlid;
#pragma unroll
  for (int e = 0; e < 8; ++e) { vone[e] = (short)oneb; vlid[e] = (short)lidb; }
  f32x4 z4 = {0.f, 0.f, 0.f, 0.f};
  f32x4 d1 = __builtin_amdgcn_mfma_f32_16x16x32_bf16(vlid, vone, z4, 0, 0, 0);
  f32x4 d2 = __builtin_amdgcn_mfma_f32_16x16x32_bf16(vone, vlid, z4, 0, 0, 0);
  int mdec[4], ndec[4];
#pragma unroll
  for (int r = 0; r < 4; ++r) {
    mdec[r] = (int)(d1[r] * 0.03125f + 0.5f) - 1;
    ndec[r] = (int)(d2[r] * 0.03125f + 0.5f) - 1;
  }

  f32x4 acc[2][2][4];  // [ct][vt][line]
#pragma unroll
  for (int a = 0; a < 2; ++a)
#pragma unroll
    for (int b = 0; b < 2; ++b)
#pragma unroll
      for (int c = 0; c < 4; ++c) acc[a][b][c] = (f32x4){0.f, 0.f, 0.f, 0.f};

  for (int g = 0; g < 9; ++g) {
    __syncthreads();
    const int dx = g / 3 - 1, dy = g % 3 - 1;
    // padded slab base: px = x+dx+1 in [0,33], py0 = y0+dy+1; 136 contiguous
    // rows cover 4 y-lines x 34 z (row rr = vy*34 + pz, pz = z'+1).
    const size_t sbase =
        (((size_t)(bi * 34 + (x + dx + 1)) * 34) + (size_t)(y0 + dy + 1)) * (34 * CIN);
    for (int c = tid; c < ROWS * CH8; c += 256) {
      int rr = c / CH8, k = (c % CH8) * 8;
      uint4 val = *(const uint4*)(Xp + sbase + (size_t)rr * CIN + k);
      *(uint4*)(&Xs[rr * CINP + k]) = val;
    }
    __syncthreads();
    for (int dz = 0; dz < 3; ++dz) {
      const int t = g * 3 + dz;
#pragma unroll
      for (int kb = 0; kb < KS; ++kb) {
        const int ko = kb * 32 + q * 8;
        s16x8 ah[2], al[2], bb[2][4];
#pragma unroll
        for (int ct = 0; ct < 2; ++ct) {
          size_t wo = ((size_t)(t * 128 + cobase + ct * 16 + l15)) * CIN + ko;
          ah[ct] = *(const s16x8*)(Wh + wo);
          al[ct] = *(const s16x8*)(Wl + wo);
        }
#pragma unroll
        for (int vt = 0; vt < 2; ++vt)
#pragma unroll
          for (int ln = 0; ln < 4; ++ln)
            bb[vt][ln] = *(const s16x8*)(&Xs[(ln * 34 + vt * 16 + l15 + dz) * CINP + ko]);
#pragma unroll
        for (int ct = 0; ct < 2; ++ct)
#pragma unroll
          for (int vt = 0; vt < 2; ++vt)
#pragma unroll
            for (int ln = 0; ln < 4; ++ln) {
              acc[ct][vt][ln] = __builtin_amdgcn_mfma_f32_16x16x32_bf16(
                  ah[ct], bb[vt][ln], acc[ct][vt][ln], 0, 0, 0);
              acc[ct][vt][ln] = __builtin_amdgcn_mfma_f32_16x16x32_bf16(
                  al[ct], bb[vt][ln], acc[ct][vt][ln], 0, 0, 0);
            }
      }
    }
  }

  // ---- epilogue: decoded scatter through LDS, 2 lines per pass ------------
  const int half = lane >> 5, zl = lane & 31;
  for (int p = 0; p < 2; ++p) {
    __syncthreads();   // drains Xs reads -> safe to overwrite
#pragma unroll
    for (int l2 = 0; l2 < 2; ++l2)
#pragma unroll
      for (int ct = 0; ct < 2; ++ct)
#pragma unroll
        for (int vt = 0; vt < 2; ++vt)
#pragma unroll
          for (int r = 0; r < 4; ++r)
            ldsW[((wave * 2 + l2) * 32 + ct * 16 + mdec[r]) * 33 + vt * 16 + ndec[r]] =
                acc[ct][vt][2 * p + l2][r];
    __syncthreads();
    const int co0 = cobase + half * 16;
#pragma unroll
    for (int l2 = 0; l2 < 2; ++l2) {
      float v[16];
#pragma unroll
      for (int j = 0; j < 16; ++j)
        v[j] = ldsW[((wave * 2 + l2) * 32 + half * 16 + j) * 33 + zl] + bias[co0 + j];
      float mu = 0.f;
#pragma unroll
      for (int j = 0; j < 16; ++j) mu += v[j];
      mu *= 0.0625f;
      float var = 0.f;
#pragma unroll
      for (int j = 0; j < 16; ++j) { float d = v[j] - mu; var = fmaf(d, d, var); }
      var *= 0.0625f;
      float rs = rsqrtf(var + 1e-5f);
#pragma unroll
      for (int j = 0; j < 16; ++j) {
        float xn = (v[j] - mu) * rs * gamma[co0 + j] + beta[co0 + j];
        v[j] = silu(xn);
      }
      size_t row;
      if (PADOUT)
        row = (((size_t)bi * 34 + x + 1) * 34 + (y0 + 2 * p + l2 + 1)) * 34 + (zl + 1);
      else
        row = (size_t)bi * R3 + (size_t)((x * 32 + y0 + 2 * p + l2) * 32 + zl);
      u16 outv[16];
#pragma unroll
      for (int j = 0; j < 16; ++j) outv[j] = f2b(v[j]);
      u16* yp = Yb + row * 128 + co0;
      *(uint4*)(yp)     = *(uint4*)(outv);
      *(uint4*)(yp + 8) = *(uint4*)(outv + 8);
    }
  }
}

// ---- K_mlp: MFMA 1x1 conv + fused global-GN stats -------------------------
__global__ void __launch_bounds__(256)
mlp_mfma(const float* __restrict__ features, const u16* __restrict__ Whm,
         const u16* __restrict__ Wlm, const float* __restrict__ mb,
         u16* __restrict__ pf, float* __restrict__ stats) {
  constexpr int XBYTES = 64 * 72 * 2;
  constexpr int SBYTES = 4 * 64 * 33 * 4;   // 4 waves x [64pt][32co+1]
  __shared__ __align__(16) char ldsbuf[(XBYTES > SBYTES) ? XBYTES : SBYTES];
  u16* Xs = (u16*)ldsbuf;
  float* ldsW = (float*)ldsbuf;

  const int tid = threadIdx.x;
  const int wave = tid >> 6, lane = tid & 63;
  const int l15 = lane & 15, q = lane >> 4;
  const int cobase = wave * 32;
  const int bi = blockIdx.x >> 8;
  const int n0 = (blockIdx.x & 255) << 6;

  // calibration (PROVEN r8)
  u16 oneb = f2b(1.0f), lidb = f2b((float)(l15 + 1));
  s16x8 vone, vlid;
#pragma unroll
  for (int e = 0; e < 8; ++e) { vone[e] = (short)oneb; vlid[e] = (short)lidb; }
  f32x4 z4 = {0.f, 0.f, 0.f, 0.f};
  f32x4 d1 = __builtin_amdgcn_mfma_f32_16x16x32_bf16(vlid, vone, z4, 0, 0, 0);
  f32x4 d2 = __builtin_amdgcn_mfma_f32_16x16x32_bf16(vone, vlid, z4, 0, 0, 0);
  int mdec[4], ndec[4];
#pragma unroll
  for (int r = 0; r < 4; ++r) {
    mdec[r] = (int)(d1[r] * 0.03125f + 0.5f) - 1;
    ndec[r] = (int)(d2[r] * 0.03125f + 0.5f) - 1;
  }

  // stage transpose: Xs[pt][ci]
  for (int e = tid; e < 4096; e += 256) {
    int ci = e >> 6, nn = e & 63;
    Xs[nn * 72 + ci] = f2b(features[((size_t)bi * 64 + ci) * NPTS + n0 + nn]);
  }
  __syncthreads();

  f32x4 acc[2][4];  // [ct][vt: 4 point-tiles of 16]
#pragma unroll
  for (int a = 0; a < 2; ++a)
#pragma unroll
    for (int b = 0; b < 4; ++b) acc[a][b] = (f32x4){0.f, 0.f, 0.f, 0.f};

#pragma unroll
  for (int kb = 0; kb < 2; ++kb) {
    const int ko = kb * 32 + q * 8;
    s16x8 ah[2], al[2], bb[4];
#pragma unroll
    for (int ct = 0; ct < 2; ++ct) {
      size_t wo = ((size_t)(cobase + ct * 16 + l15)) * 64 + ko;
      ah[ct] = *(const s16x8*)(Whm + wo);
      al[ct] = *(const s16x8*)(Wlm + wo);
    }
#pragma unroll
    for (int vt = 0; vt < 4; ++vt)
      bb[vt] = *(const s16x8*)(&Xs[(vt * 16 + l15) * 72 + ko]);
#pragma unroll
    for (int ct = 0; ct < 2; ++ct)
#pragma unroll
      for (int vt = 0; vt < 4; ++vt) {
        acc[ct][vt] = __builtin_amdgcn_mfma_f32_16x16x32_bf16(ah[ct], bb[vt], acc[ct][vt], 0, 0, 0);
        acc[ct][vt] = __builtin_amdgcn_mfma_f32_16x16x32_bf16(al[ct], bb[vt], acc[ct][vt], 0, 0, 0);
      }
  }

  // epilogue: decoded scatter -> ldsW[wave][pt][co32], then store + stats
  __syncthreads();
#pragma unroll
  for (int ct = 0; ct < 2; ++ct)
#pragma unroll
    for (int vt = 0; vt < 4; ++vt)
#pragma unroll
      for (int r = 0; r < 4; ++r)
        ldsW[(wave * 64 + vt * 16 + ndec[r]) * 33 + ct * 16 + mdec[r]] = acc[ct][vt][r];
  __syncthreads();

  float v[32];
  float s0 = 0.f, q0 = 0.f, s1 = 0.f, q1 = 0.f;
#pragma unroll
  for (int j = 0; j < 32; ++j) {
    v[j] = ldsW[(wave * 64 + lane) * 33 + j] + mb[cobase + j];
    if (j < 16) { s0 += v[j]; q0 = fmaf(v[j], v[j], q0); }
    else        { s1 += v[j]; q1 = fmaf(v[j], v[j], q1); }
  }
  u16 outv[32];
#pragma unroll
  for (int j = 0; j < 32; ++j) outv[j] = f2b(v[j]);
  u16* yp = pf + ((size_t)bi * NPTS + n0 + lane) * 128 + cobase;
#pragma unroll
  for (int k = 0; k < 4; ++k) *(uint4*)(yp + 8 * k) = *(uint4*)(outv + 8 * k);

#pragma unroll
  for (int off = 32; off > 0; off >>= 1) {
    s0 += __shfl_xor(s0, off); q0 += __shfl_xor(q0, off);
    s1 += __shfl_xor(s1, off); q1 += __shfl_xor(q1, off);
  }
  if (lane == 0) {
    atomicAdd(&stats[(bi * 8 + 2 * wave + 0) * 2 + 0], s0);
    atomicAdd(&stats[(bi * 8 + 2 * wave + 0) * 2 + 1], q0);
    atomicAdd(&stats[(bi * 8 + 2 * wave + 1) * 2 + 0], s1);
    atomicAdd(&stats[(bi * 8 + 2 * wave + 1) * 2 + 1], q1);
  }
}

// ---- K_final (proven) -----------------------------------------------------
__global__ void __launch_bounds__(256)
final_fuse(const float* __restrict__ coords, const u16* __restrict__ H,
           const u16* __restrict__ pf, const float* __restrict__ stats,
           const float* __restrict__ gg, const float* __restrict__ gb,
           float* __restrict__ out) {
  __shared__ float trans[64][130];
  const int tid = threadIdx.x;
  const int wave = tid >> 6, lane = tid & 63;
  const int bi = blockIdx.x >> 8;
  const int p0 = (blockIdx.x & 255) << 6;
  const int co = lane * 2;
  const int grp = co >> 4;
  const float cntInv = 1.f / (16.f * 16384.f);
  float S  = stats[(bi * 8 + grp) * 2 + 0];
  float SS = stats[(bi * 8 + grp) * 2 + 1];
  float mu = S * cntInv;
  float var = SS * cntInv - mu * mu;
  float rs = rsqrtf(var + 1e-5f);
  float g0 = gg[co], g1 = gg[co + 1], b0 = gb[co], b1 = gb[co + 1];

  for (int pi = 0; pi < 16; ++pi) {
    int pl = wave * 16 + pi;
    int p = p0 + pl;
    const float* cp = coords + ((size_t)bi * NPTS + p) * 3;
    float cx = cp[0] * 32.f, cy = cp[1] * 32.f, cz = cp[2] * 32.f;
    float fx = floorf(cx), fy = floorf(cy), fz = floorf(cz);
    int ix = min(max((int)fx, 0), 31);
    int iy = min(max((int)fy, 0), 31);
    int iz = min(max((int)fz, 0), 31);
    float rx = cx - fx, ry = cy - fy, rz = cz - fz;
    int hx = min(ix + 1, 31), hy = min(iy + 1, 31), hz = min(iz + 1, 31);
    float a0 = 0.f, a1 = 0.f;
#pragma unroll
    for (int k = 0; k < 8; ++k) {
      int xb = k >> 2, yb = (k >> 1) & 1, zb = k & 1;
      float w = (xb ? rx : 1.f - rx) * (yb ? ry : 1.f - ry) * (zb ? rz : 1.f - rz);
      int vi = ((xb ? hx : ix) * 32 + (yb ? hy : iy)) * 32 + (zb ? hz : iz);
      unsigned hv = *(const unsigned*)(H + ((size_t)bi * R3 + vi) * 128 + co);
      a0 += w * b2f((u16)(hv & 0xffff));
      a1 += w * b2f((u16)(hv >> 16));
    }
    unsigned pv = *(const unsigned*)(pf + ((size_t)bi * NPTS + p) * 128 + co);
    float q0 = (b2f((u16)(pv & 0xffff)) - mu) * rs * g0 + b0;
    float q1 = (b2f((u16)(pv >> 16)) - mu) * rs * g1 + b1;
    trans[pl][co]     = silu(q0) + a0;
    trans[pl][co + 1] = silu(q1) + a1;
  }
  __syncthreads();
  for (int e = tid; e < 8192; e += 256) {
    int c = e >> 6, pp = e & 63;
    out[((size_t)bi * 128 + c) * NPTS + p0 + pp] = trans[pp][c];
  }
}

// ---- host -----------------------------------------------------------------
extern "C" void kernel_launch(void* const* d_in, const int* in_sizes, int n_in,
                              void* d_out, int out_size, void* d_ws, size_t ws_size,
                              hipStream_t stream) {
  const float* coords   = (const float*)d_in[0];
  const float* features = (const float*)d_in[1];
  const float* conv1_w  = (const float*)d_in[2];
  const float* conv1_b  = (const float*)d_in[3];
  const float* gn1_g    = (const float*)d_in[4];
  const float* gn1_b    = (const float*)d_in[5];
  const float* conv2_w  = (const float*)d_in[6];
  const float* conv2_b  = (const float*)d_in[7];
  const float* gn2_g    = (const float*)d_in[8];
  const float* gn2_b    = (const float*)d_in[9];
  const float* mlp_w    = (const float*)d_in[10];
  const float* mlp_b    = (const float*)d_in[11];
  const float* gnp_g    = (const float*)d_in[12];
  const float* gnp_b    = (const float*)d_in[13];

  char* ws = (char*)d_ws;
  // layout (bytes), total ~97.4 MB:
  float* Gsum = (float*)(ws + 0);            // 33,554,432 fp32 [b][vox][64]
  u16*   H    = (u16*)(ws + 0);              // alias: bf16 [b][vox][128] (Gsum dead)
  u16*   X1p  = (u16*)(ws + 33554432);       // 20,123,648 bf16 [b][34][34][34][64]
  u16*   pf   = (u16*)(ws + 33554432);       // alias X1p (written after conv1)
  u16*   X2p  = (u16*)(ws + 53678080);       // 40,247,296 bf16 [b][34][34][34][128]
  float* Gcnt = (float*)(ws + 93925376);     // 524,288
  float* stats= (float*)(ws + 94449664);     // 4,096
  int*   pvox = (int*)(ws + 94453760);       // 262,144
  u16*   Wh1  = (u16*)(ws + 94715904);       // 442,368
  u16*   Wl1  = (u16*)(ws + 95158272);       // 442,368
  u16*   Wh2  = (u16*)(ws + 95600640);       // 884,736
  u16*   Wl2  = (u16*)(ws + 96485376);       // 884,736
  u16*   Whm  = (u16*)(ws + 97370112);       // 16,384
  u16*   Wlm  = (u16*)(ws + 97386496);       // 16,384 -> 97,402,880

  hipMemsetAsync(ws, 0, 33554432, stream);                   // Gsum
  hipMemsetAsync(ws + 33554432, 0, 60370944, stream);        // X1p+X2p (zero halo)
  hipMemsetAsync(ws + 93925376, 0, 528384, stream);          // Gcnt + stats

  convert_weights<<<(27 * 128 * 128 + 255) / 256, 256, 0, stream>>>(
      conv1_w, conv2_w, mlp_w, Wh1, Wl1, Wh2, Wl2, Whm, Wlm);
  calc_pvox<<<(4 * NPTS + 255) / 256, 256, 0, stream>>>(coords, pvox);
  scatter_feats<<<16384, 256, 0, stream>>>(features, pvox, Gsum, Gcnt);
  finalize_grid<<<32768, 256, 0, stream>>>(Gsum, Gcnt, X1p);
  conv_mfma16p<64, true><<<1024, 256, 0, stream>>>(
      X1p, Wh1, Wl1, conv1_b, gn1_g, gn1_b, X2p);
  mlp_mfma<<<1024, 256, 0, stream>>>(features, Whm, Wlm, mlp_b, pf, stats);
  conv_mfma16p<128, false><<<1024, 256, 0, stream>>>(
      X2p, Wh2, Wl2, conv2_b, gn2_g, gn2_b, H);
  final_fuse<<<1024, 256, 0, stream>>>(coords, H, pf, stats, gnp_g, gnp_b,
                                       (float*)d_out);
}

// Round 3
// 901.164 us; speedup vs baseline: 1.4536x; 1.0312x over previous
//
#include <hip/hip_runtime.h>

typedef unsigned short u16;
typedef __attribute__((ext_vector_type(8))) short s16x8;
typedef __attribute__((ext_vector_type(4))) float f32x4;

#define R3 32768
#define NPTS 16384

__device__ __forceinline__ float b2f(u16 u) {
  union { unsigned int i; float f; } v; v.i = ((unsigned int)u) << 16; return v.f;
}
__device__ __forceinline__ u16 f2b(float f) {
  union { float f; unsigned int i; } v; v.f = f;
  unsigned int x = v.i;
  return (u16)((x + 0x7fffu + ((x >> 16) & 1u)) >> 16);
}
__device__ __forceinline__ void split2(float x, u16& h, u16& l) {
  h = f2b(x); l = f2b(x - b2f(h));
}
__device__ __forceinline__ float silu(float x) {
  return x / (1.f + __expf(-x));
}

// ---- K0: weights -> hi/lo bf16. conv: [tap][co][ci]; mlp: [co][ci] --------
__global__ void convert_weights(const float* __restrict__ w1, const float* __restrict__ w2,
                                const float* __restrict__ wm,
                                u16* __restrict__ Wh1, u16* __restrict__ Wl1,
                                u16* __restrict__ Wh2, u16* __restrict__ Wl2,
                                u16* __restrict__ Whm, u16* __restrict__ Wlm) {
  int e = blockIdx.x * 256 + threadIdx.x;
  if (e < 27 * 128 * 64) {
    int t = e / (128 * 64), co = (e / 64) % 128, ci = e % 64;
    split2(w1[(co * 64 + ci) * 27 + t], Wh1[e], Wl1[e]);
  }
  if (e < 27 * 128 * 128) {
    int t = e / (128 * 128), co = (e / 128) % 128, ci = e % 128;
    split2(w2[(co * 128 + ci) * 27 + t], Wh2[e], Wl2[e]);
  }
  if (e < 128 * 64) split2(wm[e], Whm[e], Wlm[e]);
}

// ---- K_pvox (proven) ------------------------------------------------------
__global__ void calc_pvox(const float* __restrict__ coords, int* __restrict__ pvox) {
  int t = blockIdx.x * 256 + threadIdx.x;  // < 4*16384
  if (t >= 4 * NPTS) return;
  const float* cp = coords + (size_t)t * 3;
  int ix = min(max((int)floorf(cp[0] * 32.f), 0), 31);
  int iy = min(max((int)floorf(cp[1] * 32.f), 0), 31);
  int iz = min(max((int)floorf(cp[2] * 32.f), 0), 31);
  pvox[t] = (ix * 32 + iy) * 32 + iz;
}

// ---- K_scatter (proven) ---------------------------------------------------
__global__ void __launch_bounds__(256)
scatter_feats(const float* __restrict__ features, const int* __restrict__ pvox,
              float* __restrict__ Gsum, float* __restrict__ Gcnt) {
  size_t t = (size_t)blockIdx.x * 256 + threadIdx.x;  // < 4 * 2^20
  int n  = (int)(t & 16383);
  int ci = (int)((t >> 14) & 63);
  int bi = (int)(t >> 20);
  int v = pvox[bi * NPTS + n];
  float val = features[t];  // features flat [b][ci][n] index == t
  atomicAdd(&Gsum[((size_t)bi * R3 + v) * 64 + ci], val);
  if (ci == 0) atomicAdd(&Gcnt[bi * R3 + v], 1.f);
}

// ---- K_finalize: X1 = bf16(Gsum / max(cnt,1)), compact (r0-proven) --------
__global__ void __launch_bounds__(256)
finalize_grid(const float* __restrict__ Gsum, const float* __restrict__ Gcnt,
              u16* __restrict__ X1) {
  size_t t = (size_t)blockIdx.x * 256 + threadIdx.x;  // < 4*32768*64
  float c = Gcnt[t >> 6];
  X1[t] = f2b(Gsum[t] / fmaxf(c, 1.f));
}

// ---- conv: X bf16 compact [b][vox][CIN], W split hi/lo bf16 [tap][co][ci].
// r0-proven sync skeleton, restructured:
//  (1) stage per-dx: one 6-y-line x 34-z slab (204 rows) serves all 9
//      (dy,dz) taps -> staging bytes/block halved, barrier pairs 9 -> 3;
//  (2) T14 reg-staged split: next slab's bounds-checked uint4 loads issue
//      right after the LDS-write barrier, consumed one full compute phase
//      later (latency hidden under 18/36 MFMA steps);
//  (3) weight register double-buffer one step ahead + setprio(1) around
//      the 32-MFMA cluster.
// 2-term split MFMA + calibrated C/D decode (PROVEN r8/r9).
template<int CIN>
__global__ void __launch_bounds__(256, 2)
conv_mfma_t14(const u16* __restrict__ X, const u16* __restrict__ Wh,
              const u16* __restrict__ Wl, const float* __restrict__ bias,
              const float* __restrict__ gamma, const float* __restrict__ beta,
              u16* __restrict__ Yb) {
  constexpr int CINP = CIN + 8;            // LDS row stride (odd x 16B)
  constexpr int ROWS = 204;                // 6 y-lines x 34 z (y'=-1..4, z'=-1..32)
  constexpr int CH8 = CIN / 8;
  constexpr int KS = CIN / 32;
  constexpr int NCH = ROWS * CH8;          // 16B chunks per slab: 1632 / 3264
  constexpr int NLD = (NCH + 255) / 256;   // loads per thread: 7 / 13
  constexpr int NSTEP = 9 * KS;            // MFMA steps per dx phase: 18 / 36
  constexpr int XBYTES = ROWS * CINP * 2;  // 29376 / 55488
  constexpr int SBYTES = 4 * 2 * 32 * 33 * 4;   // epilogue scratch 33792
  __shared__ __align__(16) char ldsbuf[(XBYTES > SBYTES) ? XBYTES : SBYTES];
  u16* Xs = (u16*)ldsbuf;
  float* ldsW = (float*)ldsbuf;            // valid only after X reads drained

  const int tid = threadIdx.x;
  const int wave = tid >> 6, lane = tid & 63;
  const int l15 = lane & 15, q = lane >> 4;
  const int cobase = wave * 32;

  const int bi = blockIdx.x >> 8;
  const int rem = blockIdx.x & 255;
  const int x = rem >> 3, y0 = (rem & 7) << 2;

  // ---- runtime C/D calibration (PROVEN r8) ----
  u16 oneb = f2b(1.0f), lidb = f2b((float)(l15 + 1));
  s16x8 vone, vlid;
#pragma unroll
  for (int e = 0; e < 8; ++e) { vone[e] = (short)oneb; vlid[e] = (short)lidb; }
  f32x4 z4 = {0.f, 0.f, 0.f, 0.f};
  f32x4 d1 = __builtin_amdgcn_mfma_f32_16x16x32_bf16(vlid, vone, z4, 0, 0, 0);
  f32x4 d2 = __builtin_amdgcn_mfma_f32_16x16x32_bf16(vone, vlid, z4, 0, 0, 0);
  int mdec[4], ndec[4];
#pragma unroll
  for (int r = 0; r < 4; ++r) {
    mdec[r] = (int)(d1[r] * 0.03125f + 0.5f) - 1;
    ndec[r] = (int)(d2[r] * 0.03125f + 0.5f) - 1;
  }

  f32x4 acc[2][2][4];  // [ct][vt][line]
#pragma unroll
  for (int a = 0; a < 2; ++a)
#pragma unroll
    for (int b = 0; b < 2; ++b)
#pragma unroll
      for (int c = 0; c < 4; ++c) acc[a][b][c] = (f32x4){0.f, 0.f, 0.f, 0.f};

  uint4 stg[NLD];
  // stage slab for input x-plane xs = x + dxs - 1 into registers
  auto loadStage = [&](int dxs) {
    const int xs = x + dxs - 1;
    const bool xok = (xs >= 0) && (xs < 32);
#pragma unroll
    for (int j = 0; j < NLD; ++j) {
      int c = j * 256 + tid;
      uint4 v; v.x = v.y = v.z = v.w = 0u;
      if (c < NCH) {
        int rr = c / CH8, k = (c % CH8) * 8;
        int jy = rr / 34, pz = rr - jy * 34;
        int ys = y0 + jy - 1, zz = pz - 1;
        if (xok && ys >= 0 && ys < 32 && zz >= 0 && zz < 32)
          v = *(const uint4*)(X + ((size_t)bi * R3 +
                (size_t)((xs * 32 + ys) * 32 + zz)) * CIN + k);
      }
      stg[j] = v;
    }
  };

  s16x8 ah[2][2], al[2][2];
#define LOADW(T, KB, DST) do {                                                \
    const int ko_ = (KB) * 32 + q * 8;                                        \
    _Pragma("unroll")                                                         \
    for (int ct_ = 0; ct_ < 2; ++ct_) {                                       \
      size_t wo_ = ((size_t)((T) * 128 + cobase + ct_ * 16 + l15)) * CIN + ko_;\
      ah[DST][ct_] = *(const s16x8*)(Wh + wo_);                               \
      al[DST][ct_] = *(const s16x8*)(Wl + wo_);                               \
    } } while (0)

  loadStage(0);
  LOADW(0, 0, 0);

  for (int dxs = 0; dxs < 3; ++dxs) {
    __syncthreads();   // all waves done reading previous slab
#pragma unroll
    for (int j = 0; j < NLD; ++j) {
      int c = j * 256 + tid;
      if (c < NCH) {
        int rr = c / CH8, k = (c % CH8) * 8;
        *(uint4*)(&Xs[rr * CINP + k]) = stg[j];
      }
    }
    __syncthreads();
    if (dxs < 2) loadStage(dxs + 1);   // issue early; consumed next phase

#pragma unroll
    for (int s = 0; s < NSTEP; ++s) {
      const int pm = s & 1, nm = pm ^ 1;
      // weight prefetch one step ahead (t = dxs*9 + s/KS)
      if (s + 1 < NSTEP)  LOADW(dxs * 9 + (s + 1) / KS, (s + 1) % KS, nm);
      else if (dxs < 2)   LOADW((dxs + 1) * 9, 0, nm);
      const int dy = s / (3 * KS), dz = (s / KS) % 3, kb = s % KS;
      const int ko = kb * 32 + q * 8;
      s16x8 bb[2][4];
#pragma unroll
      for (int vt = 0; vt < 2; ++vt)
#pragma unroll
        for (int ln = 0; ln < 4; ++ln)
          bb[vt][ln] = *(const s16x8*)(
              &Xs[((ln + dy) * 34 + vt * 16 + l15 + dz) * CINP + ko]);
      __builtin_amdgcn_s_setprio(1);
#pragma unroll
      for (int ct = 0; ct < 2; ++ct)
#pragma unroll
        for (int vt = 0; vt < 2; ++vt)
#pragma unroll
          for (int ln = 0; ln < 4; ++ln) {
            acc[ct][vt][ln] = __builtin_amdgcn_mfma_f32_16x16x32_bf16(
                ah[pm][ct], bb[vt][ln], acc[ct][vt][ln], 0, 0, 0);
            acc[ct][vt][ln] = __builtin_amdgcn_mfma_f32_16x16x32_bf16(
                al[pm][ct], bb[vt][ln], acc[ct][vt][ln], 0, 0, 0);
          }
      __builtin_amdgcn_s_setprio(0);
    }
  }
#undef LOADW

  // ---- epilogue: decoded scatter through LDS, 2 lines per pass ------------
  const int half = lane >> 5, zl = lane & 31;
  for (int p = 0; p < 2; ++p) {
    __syncthreads();   // drains Xs reads -> safe to overwrite
#pragma unroll
    for (int l2 = 0; l2 < 2; ++l2)
#pragma unroll
      for (int ct = 0; ct < 2; ++ct)
#pragma unroll
        for (int vt = 0; vt < 2; ++vt)
#pragma unroll
          for (int r = 0; r < 4; ++r)
            ldsW[((wave * 2 + l2) * 32 + ct * 16 + mdec[r]) * 33 + vt * 16 + ndec[r]] =
                acc[ct][vt][2 * p + l2][r];
    __syncthreads();
    const int co0 = cobase + half * 16;
#pragma unroll
    for (int l2 = 0; l2 < 2; ++l2) {
      float v[16];
#pragma unroll
      for (int j = 0; j < 16; ++j)
        v[j] = ldsW[((wave * 2 + l2) * 32 + half * 16 + j) * 33 + zl] + bias[co0 + j];
      float mu = 0.f;
#pragma unroll
      for (int j = 0; j < 16; ++j) mu += v[j];
      mu *= 0.0625f;
      float var = 0.f;
#pragma unroll
      for (int j = 0; j < 16; ++j) { float d = v[j] - mu; var = fmaf(d, d, var); }
      var *= 0.0625f;
      float rs = rsqrtf(var + 1e-5f);
#pragma unroll
      for (int j = 0; j < 16; ++j) {
        float xn = (v[j] - mu) * rs * gamma[co0 + j] + beta[co0 + j];
        v[j] = silu(xn);
      }
      size_t row = (size_t)bi * R3 + (size_t)((x * 32 + y0 + 2 * p + l2) * 32 + zl);
      u16 outv[16];
#pragma unroll
      for (int j = 0; j < 16; ++j) outv[j] = f2b(v[j]);
      u16* yp = Yb + row * 128 + co0;
      *(uint4*)(yp)     = *(uint4*)(outv);
      *(uint4*)(yp + 8) = *(uint4*)(outv + 8);
    }
  }
}

// ---- K_mlp: MFMA 1x1 conv + fused global-GN stats -------------------------
__global__ void __launch_bounds__(256)
mlp_mfma(const float* __restrict__ features, const u16* __restrict__ Whm,
         const u16* __restrict__ Wlm, const float* __restrict__ mb,
         u16* __restrict__ pf, float* __restrict__ stats) {
  constexpr int XBYTES = 64 * 72 * 2;
  constexpr int SBYTES = 4 * 64 * 33 * 4;   // 4 waves x [64pt][32co+1]
  __shared__ __align__(16) char ldsbuf[(XBYTES > SBYTES) ? XBYTES : SBYTES];
  u16* Xs = (u16*)ldsbuf;
  float* ldsW = (float*)ldsbuf;

  const int tid = threadIdx.x;
  const int wave = tid >> 6, lane = tid & 63;
  const int l15 = lane & 15, q = lane >> 4;
  const int cobase = wave * 32;
  const int bi = blockIdx.x >> 8;
  const int n0 = (blockIdx.x & 255) << 6;

  // calibration (PROVEN r8)
  u16 oneb = f2b(1.0f), lidb = f2b((float)(l15 + 1));
  s16x8 vone, vlid;
#pragma unroll
  for (int e = 0; e < 8; ++e) { vone[e] = (short)oneb; vlid[e] = (short)lidb; }
  f32x4 z4 = {0.f, 0.f, 0.f, 0.f};
  f32x4 d1 = __builtin_amdgcn_mfma_f32_16x16x32_bf16(vlid, vone, z4, 0, 0, 0);
  f32x4 d2 = __builtin_amdgcn_mfma_f32_16x16x32_bf16(vone, vlid, z4, 0, 0, 0);
  int mdec[4], ndec[4];
#pragma unroll
  for (int r = 0; r < 4; ++r) {
    mdec[r] = (int)(d1[r] * 0.03125f + 0.5f) - 1;
    ndec[r] = (int)(d2[r] * 0.03125f + 0.5f) - 1;
  }

  // stage transpose: Xs[pt][ci]
  for (int e = tid; e < 4096; e += 256) {
    int ci = e >> 6, nn = e & 63;
    Xs[nn * 72 + ci] = f2b(features[((size_t)bi * 64 + ci) * NPTS + n0 + nn]);
  }
  __syncthreads();

  f32x4 acc[2][4];  // [ct][vt: 4 point-tiles of 16]
#pragma unroll
  for (int a = 0; a < 2; ++a)
#pragma unroll
    for (int b = 0; b < 4; ++b) acc[a][b] = (f32x4){0.f, 0.f, 0.f, 0.f};

#pragma unroll
  for (int kb = 0; kb < 2; ++kb) {
    const int ko = kb * 32 + q * 8;
    s16x8 ah[2], al[2], bb[4];
#pragma unroll
    for (int ct = 0; ct < 2; ++ct) {
      size_t wo = ((size_t)(cobase + ct * 16 + l15)) * 64 + ko;
      ah[ct] = *(const s16x8*)(Whm + wo);
      al[ct] = *(const s16x8*)(Wlm + wo);
    }
#pragma unroll
    for (int vt = 0; vt < 4; ++vt)
      bb[vt] = *(const s16x8*)(&Xs[(vt * 16 + l15) * 72 + ko]);
#pragma unroll
    for (int ct = 0; ct < 2; ++ct)
#pragma unroll
      for (int vt = 0; vt < 4; ++vt) {
        acc[ct][vt] = __builtin_amdgcn_mfma_f32_16x16x32_bf16(ah[ct], bb[vt], acc[ct][vt], 0, 0, 0);
        acc[ct][vt] = __builtin_amdgcn_mfma_f32_16x16x32_bf16(al[ct], bb[vt], acc[ct][vt], 0, 0, 0);
      }
  }

  // epilogue: decoded scatter -> ldsW[wave][pt][co32], then store + stats
  __syncthreads();
#pragma unroll
  for (int ct = 0; ct < 2; ++ct)
#pragma unroll
    for (int vt = 0; vt < 4; ++vt)
#pragma unroll
      for (int r = 0; r < 4; ++r)
        ldsW[(wave * 64 + vt * 16 + ndec[r]) * 33 + ct * 16 + mdec[r]] = acc[ct][vt][r];
  __syncthreads();

  float v[32];
  float s0 = 0.f, q0 = 0.f, s1 = 0.f, q1 = 0.f;
#pragma unroll
  for (int j = 0; j < 32; ++j) {
    v[j] = ldsW[(wave * 64 + lane) * 33 + j] + mb[cobase + j];
    if (j < 16) { s0 += v[j]; q0 = fmaf(v[j], v[j], q0); }
    else        { s1 += v[j]; q1 = fmaf(v[j], v[j], q1); }
  }
  u16 outv[32];
#pragma unroll
  for (int j = 0; j < 32; ++j) outv[j] = f2b(v[j]);
  u16* yp = pf + ((size_t)bi * NPTS + n0 + lane) * 128 + cobase;
#pragma unroll
  for (int k = 0; k < 4; ++k) *(uint4*)(yp + 8 * k) = *(uint4*)(outv + 8 * k);

#pragma unroll
  for (int off = 32; off > 0; off >>= 1) {
    s0 += __shfl_xor(s0, off); q0 += __shfl_xor(q0, off);
    s1 += __shfl_xor(s1, off); q1 += __shfl_xor(q1, off);
  }
  if (lane == 0) {
    atomicAdd(&stats[(bi * 8 + 2 * wave + 0) * 2 + 0], s0);
    atomicAdd(&stats[(bi * 8 + 2 * wave + 0) * 2 + 1], q0);
    atomicAdd(&stats[(bi * 8 + 2 * wave + 1) * 2 + 0], s1);
    atomicAdd(&stats[(bi * 8 + 2 * wave + 1) * 2 + 1], q1);
  }
}

// ---- K_final (proven) -----------------------------------------------------
__global__ void __launch_bounds__(256)
final_fuse(const float* __restrict__ coords, const u16* __restrict__ H,
           const u16* __restrict__ pf, const float* __restrict__ stats,
           const float* __restrict__ gg, const float* __restrict__ gb,
           float* __restrict__ out) {
  __shared__ float trans[64][130];
  const int tid = threadIdx.x;
  const int wave = tid >> 6, lane = tid & 63;
  const int bi = blockIdx.x >> 8;
  const int p0 = (blockIdx.x & 255) << 6;
  const int co = lane * 2;
  const int grp = co >> 4;
  const float cntInv = 1.f / (16.f * 16384.f);
  float S  = stats[(bi * 8 + grp) * 2 + 0];
  float SS = stats[(bi * 8 + grp) * 2 + 1];
  float mu = S * cntInv;
  float var = SS * cntInv - mu * mu;
  float rs = rsqrtf(var + 1e-5f);
  float g0 = gg[co], g1 = gg[co + 1], b0 = gb[co], b1 = gb[co + 1];

  for (int pi = 0; pi < 16; ++pi) {
    int pl = wave * 16 + pi;
    int p = p0 + pl;
    const float* cp = coords + ((size_t)bi * NPTS + p) * 3;
    float cx = cp[0] * 32.f, cy = cp[1] * 32.f, cz = cp[2] * 32.f;
    float fx = floorf(cx), fy = floorf(cy), fz = floorf(cz);
    int ix = min(max((int)fx, 0), 31);
    int iy = min(max((int)fy, 0), 31);
    int iz = min(max((int)fz, 0), 31);
    float rx = cx - fx, ry = cy - fy, rz = cz - fz;
    int hx = min(ix + 1, 31), hy = min(iy + 1, 31), hz = min(iz + 1, 31);
    float a0 = 0.f, a1 = 0.f;
#pragma unroll
    for (int k = 0; k < 8; ++k) {
      int xb = k >> 2, yb = (k >> 1) & 1, zb = k & 1;
      float w = (xb ? rx : 1.f - rx) * (yb ? ry : 1.f - ry) * (zb ? rz : 1.f - rz);
      int vi = ((xb ? hx : ix) * 32 + (yb ? hy : iy)) * 32 + (zb ? hz : iz);
      unsigned hv = *(const unsigned*)(H + ((size_t)bi * R3 + vi) * 128 + co);
      a0 += w * b2f((u16)(hv & 0xffff));
      a1 += w * b2f((u16)(hv >> 16));
    }
    unsigned pv = *(const unsigned*)(pf + ((size_t)bi * NPTS + p) * 128 + co);
    float q0 = (b2f((u16)(pv & 0xffff)) - mu) * rs * g0 + b0;
    float q1 = (b2f((u16)(pv >> 16)) - mu) * rs * g1 + b1;
    trans[pl][co]     = silu(q0) + a0;
    trans[pl][co + 1] = silu(q1) + a1;
  }
  __syncthreads();
  for (int e = tid; e < 8192; e += 256) {
    int c = e >> 6, pp = e & 63;
    out[((size_t)bi * 128 + c) * NPTS + p0 + pp] = trans[pp][c];
  }
}

// ---- host -----------------------------------------------------------------
extern "C" void kernel_launch(void* const* d_in, const int* in_sizes, int n_in,
                              void* d_out, int out_size, void* d_ws, size_t ws_size,
                              hipStream_t stream) {
  const float* coords   = (const float*)d_in[0];
  const float* features = (const float*)d_in[1];
  const float* conv1_w  = (const float*)d_in[2];
  const float* conv1_b  = (const float*)d_in[3];
  const float* gn1_g    = (const float*)d_in[4];
  const float* gn1_b    = (const float*)d_in[5];
  const float* conv2_w  = (const float*)d_in[6];
  const float* conv2_b  = (const float*)d_in[7];
  const float* gn2_g    = (const float*)d_in[8];
  const float* gn2_b    = (const float*)d_in[9];
  const float* mlp_w    = (const float*)d_in[10];
  const float* mlp_b    = (const float*)d_in[11];
  const float* gnp_g    = (const float*)d_in[12];
  const float* gnp_b    = (const float*)d_in[13];

  char* ws = (char*)d_ws;
  // layout (bytes) -- r0-proven compact layout (~104 MB):
  float* Gsum = (float*)(ws + 0);            // 33554432 fp32 [b][vox][64]; H bf16 aliases after conv1
  u16*   H    = (u16*)(ws + 0);              // 33554432 bf16 [b][vox][128]
  u16*   X1   = (u16*)(ws + 33554432);       // 16777216 bf16 [b][vox][64]  -> 50331648
  u16*   X2   = (u16*)(ws + 50331648);       // 33554432 bf16 [b][vox][128] -> 83886080
  float* Gcnt = (float*)(ws + 83886080);     // 524288   -> 84410368
  float* stats = (float*)(ws + 84410368);    // 4096     -> 84414464
  int*   pvox = (int*)(ws + 84414464);       // 262144   -> 84676608
  u16*   pf   = (u16*)(ws + 84676608);       // 16777216 -> 101453824
  u16*   Wh1  = (u16*)(ws + 101453824);      // 442368   -> 101896192
  u16*   Wl1  = (u16*)(ws + 101896192);      // 442368   -> 102338560
  u16*   Wh2  = (u16*)(ws + 102338560);      // 884736   -> 103223296
  u16*   Wl2  = (u16*)(ws + 103223296);      // 884736   -> 104108032
  u16*   Whm  = (u16*)(ws + 104108032);      // 16384    -> 104124416
  u16*   Wlm  = (u16*)(ws + 104124416);      // 16384    -> 104140800 (~104 MB)

  hipMemsetAsync(ws, 0, 33554432, stream);                   // Gsum
  hipMemsetAsync(ws + 83886080, 0, 524288 + 4096, stream);   // Gcnt + stats

  convert_weights<<<(27 * 128 * 128 + 255) / 256, 256, 0, stream>>>(
      conv1_w, conv2_w, mlp_w, Wh1, Wl1, Wh2, Wl2, Whm, Wlm);
  calc_pvox<<<(4 * NPTS + 255) / 256, 256, 0, stream>>>(coords, pvox);
  scatter_feats<<<16384, 256, 0, stream>>>(features, pvox, Gsum, Gcnt);
  finalize_grid<<<32768, 256, 0, stream>>>(Gsum, Gcnt, X1);
  conv_mfma_t14<64><<<1024, 256, 0, stream>>>(
      X1, Wh1, Wl1, conv1_b, gn1_g, gn1_b, X2);
  mlp_mfma<<<1024, 256, 0, stream>>>(features, Whm, Wlm, mlp_b, pf, stats);
  conv_mfma_t14<128><<<1024, 256, 0, stream>>>(
      X2, Wh2, Wl2, conv2_b, gn2_g, gn2_b, H);
  final_fuse<<<1024, 256, 0, stream>>>(coords, H, pf, stats, gnp_g, gnp_b,
                                       (float*)d_out);
}

// Round 4
// 878.437 us; speedup vs baseline: 1.4912x; 1.0259x over previous
//
#include <hip/hip_runtime.h>

typedef unsigned short u16;
typedef __attribute__((ext_vector_type(8))) short s16x8;
typedef __attribute__((ext_vector_type(4))) float f32x4;

#define R3 32768
#define NPTS 16384

__device__ __forceinline__ float b2f(u16 u) {
  union { unsigned int i; float f; } v; v.i = ((unsigned int)u) << 16; return v.f;
}
__device__ __forceinline__ u16 f2b(float f) {
  union { float f; unsigned int i; } v; v.f = f;
  unsigned int x = v.i;
  return (u16)((x + 0x7fffu + ((x >> 16) & 1u)) >> 16);
}
__device__ __forceinline__ void split2(float x, u16& h, u16& l) {
  h = f2b(x); l = f2b(x - b2f(h));
}
__device__ __forceinline__ float silu(float x) {
  return x / (1.f + __expf(-x));
}

// ---- K0: weights -> hi/lo bf16. conv: [tap][co][ci]; mlp: [co][ci] --------
__global__ void convert_weights(const float* __restrict__ w1, const float* __restrict__ w2,
                                const float* __restrict__ wm,
                                u16* __restrict__ Wh1, u16* __restrict__ Wl1,
                                u16* __restrict__ Wh2, u16* __restrict__ Wl2,
                                u16* __restrict__ Whm, u16* __restrict__ Wlm) {
  int e = blockIdx.x * 256 + threadIdx.x;
  if (e < 27 * 128 * 64) {
    int t = e / (128 * 64), co = (e / 64) % 128, ci = e % 64;
    split2(w1[(co * 64 + ci) * 27 + t], Wh1[e], Wl1[e]);
  }
  if (e < 27 * 128 * 128) {
    int t = e / (128 * 128), co = (e / 128) % 128, ci = e % 128;
    split2(w2[(co * 128 + ci) * 27 + t], Wh2[e], Wl2[e]);
  }
  if (e < 128 * 64) split2(wm[e], Whm[e], Wlm[e]);
}

// ---- K_pvox (proven) ------------------------------------------------------
__global__ void calc_pvox(const float* __restrict__ coords, int* __restrict__ pvox) {
  int t = blockIdx.x * 256 + threadIdx.x;  // < 4*16384
  if (t >= 4 * NPTS) return;
  const float* cp = coords + (size_t)t * 3;
  int ix = min(max((int)floorf(cp[0] * 32.f), 0), 31);
  int iy = min(max((int)floorf(cp[1] * 32.f), 0), 31);
  int iz = min(max((int)floorf(cp[2] * 32.f), 0), 31);
  pvox[t] = (ix * 32 + iy) * 32 + iz;
}

// ---- K_scatter (proven) ---------------------------------------------------
__global__ void __launch_bounds__(256)
scatter_feats(const float* __restrict__ features, const int* __restrict__ pvox,
              float* __restrict__ Gsum, float* __restrict__ Gcnt) {
  size_t t = (size_t)blockIdx.x * 256 + threadIdx.x;  // < 4 * 2^20
  int n  = (int)(t & 16383);
  int ci = (int)((t >> 14) & 63);
  int bi = (int)(t >> 20);
  int v = pvox[bi * NPTS + n];
  float val = features[t];  // features flat [b][ci][n] index == t
  atomicAdd(&Gsum[((size_t)bi * R3 + v) * 64 + ci], val);
  if (ci == 0) atomicAdd(&Gcnt[bi * R3 + v], 1.f);
}

// ---- K_finalize: X1 = bf16(Gsum / max(cnt,1)) -----------------------------
__global__ void __launch_bounds__(256)
finalize_grid(const float* __restrict__ Gsum, const float* __restrict__ Gcnt,
              u16* __restrict__ X1) {
  size_t t = (size_t)blockIdx.x * 256 + threadIdx.x;  // < 4*32768*64
  float c = Gcnt[t >> 6];
  X1[t] = f2b(Gsum[t] / fmaxf(c, 1.f));
}

// ---- conv: X bf16 [b][vox][CIN], W split hi/lo bf16 [tap][128co][ci] ------
// r0-proven structure (compact layout, sync staging, 38 MB fetch) with ONE
// change: register double-buffer of per-step operands. Weights (ah/al) and
// B-fragments (bb) for step s+1 are loaded while step s's 32 MFMAs issue;
// W for next g's step 0 prefetches across the stage barrier. setprio(1)
// around the MFMA cluster. Plain launch_bounds(256): compiler free to use
// ~160 arch VGPR (no (.,2) 128-cap -> no r3-style scratch spill); +64 AGPR
// stays <= 256 total -> 2 waves/SIMD unchanged.
// 2-term split MFMA + calibrated C/D decode (PROVEN r8/r9).
template<int CIN>
__global__ void __launch_bounds__(256)
conv_mfma16w(const u16* __restrict__ X, const u16* __restrict__ Wh, const u16* __restrict__ Wl,
             const float* __restrict__ bias, const float* __restrict__ gamma,
             const float* __restrict__ beta, u16* __restrict__ Yb) {
  constexpr int CINP = CIN + 8;            // row stride (odd x 16B)
  constexpr int ROWS = 136;                // 4 y-lines x 34 z-halo
  constexpr int CH8 = CIN / 8;
  constexpr int KS = CIN / 32;
  constexpr int NSTEP = 3 * KS;            // steps per tap-group g
  constexpr int XBYTES = ROWS * CINP * 2;
  constexpr int SBYTES = 4 * 2 * 32 * 33 * 4;   // 4 waves x 2 lines x [32co][33z]
  __shared__ __align__(16) char ldsbuf[(XBYTES > SBYTES) ? XBYTES : SBYTES];
  u16* Xs = (u16*)ldsbuf;
  float* ldsW = (float*)ldsbuf;            // valid only after X reads drained

  const int tid = threadIdx.x;
  const int wave = tid >> 6, lane = tid & 63;
  const int l15 = lane & 15, q = lane >> 4;
  const int cobase = wave * 32;

  const int bi = blockIdx.x >> 8;
  const int rem = blockIdx.x & 255;
  const int x = rem >> 3, y0 = (rem & 7) << 2;

  // ---- runtime C/D calibration (PROVEN r8) ----
  u16 oneb = f2b(1.0f), lidb = f2b((float)(l15 + 1));
  s16x8 vone, vlid;
#pragma unroll
  for (int e = 0; e < 8; ++e) { vone[e] = (short)oneb; vlid[e] = (short)lidb; }
  f32x4 z4 = {0.f, 0.f, 0.f, 0.f};
  f32x4 d1 = __builtin_amdgcn_mfma_f32_16x16x32_bf16(vlid, vone, z4, 0, 0, 0);
  f32x4 d2 = __builtin_amdgcn_mfma_f32_16x16x32_bf16(vone, vlid, z4, 0, 0, 0);
  int mdec[4], ndec[4];
#pragma unroll
  for (int r = 0; r < 4; ++r) {
    mdec[r] = (int)(d1[r] * 0.03125f + 0.5f) - 1;
    ndec[r] = (int)(d2[r] * 0.03125f + 0.5f) - 1;
  }

  f32x4 acc[2][2][4];  // [ct][vt][line]
#pragma unroll
  for (int a = 0; a < 2; ++a)
#pragma unroll
    for (int b = 0; b < 2; ++b)
#pragma unroll
      for (int c = 0; c < 4; ++c) acc[a][b][c] = (f32x4){0.f, 0.f, 0.f, 0.f};

  s16x8 ah[2][2], al[2][2], bb[2][2][4];

#define LOADW(T, KB, DST) do {                                                \
    const int ko_ = (KB) * 32 + q * 8;                                        \
    _Pragma("unroll")                                                         \
    for (int ct_ = 0; ct_ < 2; ++ct_) {                                       \
      size_t wo_ = ((size_t)((T) * 128 + cobase + ct_ * 16 + l15)) * CIN + ko_;\
      ah[DST][ct_] = *(const s16x8*)(Wh + wo_);                               \
      al[DST][ct_] = *(const s16x8*)(Wl + wo_);                               \
    } } while (0)

#define LOADB(DZ, KB, DST) do {                                               \
    const int ko_ = (KB) * 32 + q * 8;                                        \
    _Pragma("unroll")                                                         \
    for (int vt_ = 0; vt_ < 2; ++vt_)                                         \
      _Pragma("unroll")                                                       \
      for (int ln_ = 0; ln_ < 4; ++ln_)                                       \
        bb[DST][vt_][ln_] = *(const s16x8*)(                                  \
            &Xs[(ln_ * 34 + vt_ * 16 + l15 + (DZ)) * CINP + ko_]);            \
    } while (0)

  LOADW(0, 0, 0);   // weights for (g=0, step 0)

  for (int g = 0; g < 9; ++g) {
    __syncthreads();
    const int dx = g / 3 - 1, dy = g % 3 - 1;
    const int xs = x + dx;
    for (int c = tid; c < ROWS * CH8; c += 256) {   // r0-proven staging
      int rr = c / CH8, k = (c % CH8) * 8;
      uint4 val; val.x = val.y = val.z = val.w = 0u;
      int vy = rr / 34;                    // 0..3
      int zz = rr - vy * 34 - 1;           // z' in [-1,32]
      int ys = y0 + vy + dy;
      if (xs >= 0 && xs < 32 && ys >= 0 && ys < 32 && zz >= 0 && zz < 32)
        val = *(const uint4*)(X + ((size_t)bi * R3 + (size_t)((xs * 32 + ys) * 32 + zz)) * CIN + k);
      *(uint4*)(&Xs[rr * CINP + k]) = val;
    }
    __syncthreads();
    LOADB(0, 0, 0);  // B-fragments for step 0 of this g

#pragma unroll
    for (int s = 0; s < NSTEP; ++s) {
      const int pm = s & 1, nm = pm ^ 1;
      // prefetch step s+1 operands (or next g's step-0 weights) BEFORE MFMAs
      if (s + 1 < NSTEP) {
        LOADW(g * 3 + (s + 1) / KS, (s + 1) % KS, nm);
        LOADB((s + 1) / KS, (s + 1) % KS, nm);
      } else if (g < 8) {
        LOADW((g + 1) * 3, 0, nm);   // NSTEP even -> lands in buf 0 = next g's pm
      }
      __builtin_amdgcn_s_setprio(1);
#pragma unroll
      for (int ct = 0; ct < 2; ++ct)
#pragma unroll
        for (int vt = 0; vt < 2; ++vt)
#pragma unroll
          for (int ln = 0; ln < 4; ++ln) {
            acc[ct][vt][ln] = __builtin_amdgcn_mfma_f32_16x16x32_bf16(
                ah[pm][ct], bb[pm][vt][ln], acc[ct][vt][ln], 0, 0, 0);
            acc[ct][vt][ln] = __builtin_amdgcn_mfma_f32_16x16x32_bf16(
                al[pm][ct], bb[pm][vt][ln], acc[ct][vt][ln], 0, 0, 0);
          }
      __builtin_amdgcn_s_setprio(0);
    }
  }
#undef LOADW
#undef LOADB

  // ---- epilogue: decoded scatter through LDS, 2 lines per pass ------------
  const int half = lane >> 5, zl = lane & 31;
  for (int p = 0; p < 2; ++p) {
    __syncthreads();   // drains Xs reads -> safe to overwrite
#pragma unroll
    for (int l2 = 0; l2 < 2; ++l2)
#pragma unroll
      for (int ct = 0; ct < 2; ++ct)
#pragma unroll
        for (int vt = 0; vt < 2; ++vt)
#pragma unroll
          for (int r = 0; r < 4; ++r)
            ldsW[((wave * 2 + l2) * 32 + ct * 16 + mdec[r]) * 33 + vt * 16 + ndec[r]] =
                acc[ct][vt][2 * p + l2][r];
    __syncthreads();
    const int co0 = cobase + half * 16;
#pragma unroll
    for (int l2 = 0; l2 < 2; ++l2) {
      float v[16];
#pragma unroll
      for (int j = 0; j < 16; ++j)
        v[j] = ldsW[((wave * 2 + l2) * 32 + half * 16 + j) * 33 + zl] + bias[co0 + j];
      float mu = 0.f;
#pragma unroll
      for (int j = 0; j < 16; ++j) mu += v[j];
      mu *= 0.0625f;
      float var = 0.f;
#pragma unroll
      for (int j = 0; j < 16; ++j) { float d = v[j] - mu; var = fmaf(d, d, var); }
      var *= 0.0625f;
      float rs = rsqrtf(var + 1e-5f);
#pragma unroll
      for (int j = 0; j < 16; ++j) {
        float xn = (v[j] - mu) * rs * gamma[co0 + j] + beta[co0 + j];
        v[j] = silu(xn);
      }
      size_t row = (size_t)bi * R3 + (size_t)((x * 32 + y0 + 2 * p + l2) * 32 + zl);
      u16 outv[16];
#pragma unroll
      for (int j = 0; j < 16; ++j) outv[j] = f2b(v[j]);
      u16* yp = Yb + row * 128 + co0;
      *(uint4*)(yp)     = *(uint4*)(outv);
      *(uint4*)(yp + 8) = *(uint4*)(outv + 8);
    }
  }
}

// ---- K_mlp: MFMA 1x1 conv + fused global-GN stats -------------------------
__global__ void __launch_bounds__(256)
mlp_mfma(const float* __restrict__ features, const u16* __restrict__ Whm,
         const u16* __restrict__ Wlm, const float* __restrict__ mb,
         u16* __restrict__ pf, float* __restrict__ stats) {
  constexpr int XBYTES = 64 * 72 * 2;
  constexpr int SBYTES = 4 * 64 * 33 * 4;   // 4 waves x [64pt][32co+1]
  __shared__ __align__(16) char ldsbuf[(XBYTES > SBYTES) ? XBYTES : SBYTES];
  u16* Xs = (u16*)ldsbuf;
  float* ldsW = (float*)ldsbuf;

  const int tid = threadIdx.x;
  const int wave = tid >> 6, lane = tid & 63;
  const int l15 = lane & 15, q = lane >> 4;
  const int cobase = wave * 32;
  const int bi = blockIdx.x >> 8;
  const int n0 = (blockIdx.x & 255) << 6;

  // calibration (PROVEN r8)
  u16 oneb = f2b(1.0f), lidb = f2b((float)(l15 + 1));
  s16x8 vone, vlid;
#pragma unroll
  for (int e = 0; e < 8; ++e) { vone[e] = (short)oneb; vlid[e] = (short)lidb; }
  f32x4 z4 = {0.f, 0.f, 0.f, 0.f};
  f32x4 d1 = __builtin_amdgcn_mfma_f32_16x16x32_bf16(vlid, vone, z4, 0, 0, 0);
  f32x4 d2 = __builtin_amdgcn_mfma_f32_16x16x32_bf16(vone, vlid, z4, 0, 0, 0);
  int mdec[4], ndec[4];
#pragma unroll
  for (int r = 0; r < 4; ++r) {
    mdec[r] = (int)(d1[r] * 0.03125f + 0.5f) - 1;
    ndec[r] = (int)(d2[r] * 0.03125f + 0.5f) - 1;
  }

  // stage transpose: Xs[pt][ci]
  for (int e = tid; e < 4096; e += 256) {
    int ci = e >> 6, nn = e & 63;
    Xs[nn * 72 + ci] = f2b(features[((size_t)bi * 64 + ci) * NPTS + n0 + nn]);
  }
  __syncthreads();

  f32x4 acc[2][4];  // [ct][vt: 4 point-tiles of 16]
#pragma unroll
  for (int a = 0; a < 2; ++a)
#pragma unroll
    for (int b = 0; b < 4; ++b) acc[a][b] = (f32x4){0.f, 0.f, 0.f, 0.f};

#pragma unroll
  for (int kb = 0; kb < 2; ++kb) {
    const int ko = kb * 32 + q * 8;
    s16x8 ah[2], al[2], bb[4];
#pragma unroll
    for (int ct = 0; ct < 2; ++ct) {
      size_t wo = ((size_t)(cobase + ct * 16 + l15)) * 64 + ko;
      ah[ct] = *(const s16x8*)(Whm + wo);
      al[ct] = *(const s16x8*)(Wlm + wo);
    }
#pragma unroll
    for (int vt = 0; vt < 4; ++vt)
      bb[vt] = *(const s16x8*)(&Xs[(vt * 16 + l15) * 72 + ko]);
#pragma unroll
    for (int ct = 0; ct < 2; ++ct)
#pragma unroll
      for (int vt = 0; vt < 4; ++vt) {
        acc[ct][vt] = __builtin_amdgcn_mfma_f32_16x16x32_bf16(ah[ct], bb[vt], acc[ct][vt], 0, 0, 0);
        acc[ct][vt] = __builtin_amdgcn_mfma_f32_16x16x32_bf16(al[ct], bb[vt], acc[ct][vt], 0, 0, 0);
      }
  }

  // epilogue: decoded scatter -> ldsW[wave][pt][co32], then store + stats
  __syncthreads();
#pragma unroll
  for (int ct = 0; ct < 2; ++ct)
#pragma unroll
    for (int vt = 0; vt < 4; ++vt)
#pragma unroll
      for (int r = 0; r < 4; ++r)
        ldsW[(wave * 64 + vt * 16 + ndec[r]) * 33 + ct * 16 + mdec[r]] = acc[ct][vt][r];
  __syncthreads();

  float v[32];
  float s0 = 0.f, q0 = 0.f, s1 = 0.f, q1 = 0.f;
#pragma unroll
  for (int j = 0; j < 32; ++j) {
    v[j] = ldsW[(wave * 64 + lane) * 33 + j] + mb[cobase + j];
    if (j < 16) { s0 += v[j]; q0 = fmaf(v[j], v[j], q0); }
    else        { s1 += v[j]; q1 = fmaf(v[j], v[j], q1); }
  }
  u16 outv[32];
#pragma unroll
  for (int j = 0; j < 32; ++j) outv[j] = f2b(v[j]);
  u16* yp = pf + ((size_t)bi * NPTS + n0 + lane) * 128 + cobase;
#pragma unroll
  for (int k = 0; k < 4; ++k) *(uint4*)(yp + 8 * k) = *(uint4*)(outv + 8 * k);

#pragma unroll
  for (int off = 32; off > 0; off >>= 1) {
    s0 += __shfl_xor(s0, off); q0 += __shfl_xor(q0, off);
    s1 += __shfl_xor(s1, off); q1 += __shfl_xor(q1, off);
  }
  if (lane == 0) {
    atomicAdd(&stats[(bi * 8 + 2 * wave + 0) * 2 + 0], s0);
    atomicAdd(&stats[(bi * 8 + 2 * wave + 0) * 2 + 1], q0);
    atomicAdd(&stats[(bi * 8 + 2 * wave + 1) * 2 + 0], s1);
    atomicAdd(&stats[(bi * 8 + 2 * wave + 1) * 2 + 1], q1);
  }
}

// ---- K_final (proven) -----------------------------------------------------
__global__ void __launch_bounds__(256)
final_fuse(const float* __restrict__ coords, const u16* __restrict__ H,
           const u16* __restrict__ pf, const float* __restrict__ stats,
           const float* __restrict__ gg, const float* __restrict__ gb,
           float* __restrict__ out) {
  __shared__ float trans[64][130];
  const int tid = threadIdx.x;
  const int wave = tid >> 6, lane = tid & 63;
  const int bi = blockIdx.x >> 8;
  const int p0 = (blockIdx.x & 255) << 6;
  const int co = lane * 2;
  const int grp = co >> 4;
  const float cntInv = 1.f / (16.f * 16384.f);
  float S  = stats[(bi * 8 + grp) * 2 + 0];
  float SS = stats[(bi * 8 + grp) * 2 + 1];
  float mu = S * cntInv;
  float var = SS * cntInv - mu * mu;
  float rs = rsqrtf(var + 1e-5f);
  float g0 = gg[co], g1 = gg[co + 1], b0 = gb[co], b1 = gb[co + 1];

  for (int pi = 0; pi < 16; ++pi) {
    int pl = wave * 16 + pi;
    int p = p0 + pl;
    const float* cp = coords + ((size_t)bi * NPTS + p) * 3;
    float cx = cp[0] * 32.f, cy = cp[1] * 32.f, cz = cp[2] * 32.f;
    float fx = floorf(cx), fy = floorf(cy), fz = floorf(cz);
    int ix = min(max((int)fx, 0), 31);
    int iy = min(max((int)fy, 0), 31);
    int iz = min(max((int)fz, 0), 31);
    float rx = cx - fx, ry = cy - fy, rz = cz - fz;
    int hx = min(ix + 1, 31), hy = min(iy + 1, 31), hz = min(iz + 1, 31);
    float a0 = 0.f, a1 = 0.f;
#pragma unroll
    for (int k = 0; k < 8; ++k) {
      int xb = k >> 2, yb = (k >> 1) & 1, zb = k & 1;
      float w = (xb ? rx : 1.f - rx) * (yb ? ry : 1.f - ry) * (zb ? rz : 1.f - rz);
      int vi = ((xb ? hx : ix) * 32 + (yb ? hy : iy)) * 32 + (zb ? hz : iz);
      unsigned hv = *(const unsigned*)(H + ((size_t)bi * R3 + vi) * 128 + co);
      a0 += w * b2f((u16)(hv & 0xffff));
      a1 += w * b2f((u16)(hv >> 16));
    }
    unsigned pv = *(const unsigned*)(pf + ((size_t)bi * NPTS + p) * 128 + co);
    float q0 = (b2f((u16)(pv & 0xffff)) - mu) * rs * g0 + b0;
    float q1 = (b2f((u16)(pv >> 16)) - mu) * rs * g1 + b1;
    trans[pl][co]     = silu(q0) + a0;
    trans[pl][co + 1] = silu(q1) + a1;
  }
  __syncthreads();
  for (int e = tid; e < 8192; e += 256) {
    int c = e >> 6, pp = e & 63;
    out[((size_t)bi * 128 + c) * NPTS + p0 + pp] = trans[pp][c];
  }
}

// ---- host -----------------------------------------------------------------
extern "C" void kernel_launch(void* const* d_in, const int* in_sizes, int n_in,
                              void* d_out, int out_size, void* d_ws, size_t ws_size,
                              hipStream_t stream) {
  const float* coords   = (const float*)d_in[0];
  const float* features = (const float*)d_in[1];
  const float* conv1_w  = (const float*)d_in[2];
  const float* conv1_b  = (const float*)d_in[3];
  const float* gn1_g    = (const float*)d_in[4];
  const float* gn1_b    = (const float*)d_in[5];
  const float* conv2_w  = (const float*)d_in[6];
  const float* conv2_b  = (const float*)d_in[7];
  const float* gn2_g    = (const float*)d_in[8];
  const float* gn2_b    = (const float*)d_in[9];
  const float* mlp_w    = (const float*)d_in[10];
  const float* mlp_b    = (const float*)d_in[11];
  const float* gnp_g    = (const float*)d_in[12];
  const float* gnp_b    = (const float*)d_in[13];

  char* ws = (char*)d_ws;
  // layout (bytes) -- r0-proven compact layout (~104 MB):
  float* Gsum = (float*)(ws + 0);            // 33554432 fp32 [b][vox][64]; H bf16 aliases after conv1
  u16*   H    = (u16*)(ws + 0);              // 33554432 bf16 [b][vox][128]
  u16*   X1   = (u16*)(ws + 33554432);       // 16777216 bf16 [b][vox][64]  -> 50331648
  u16*   X2   = (u16*)(ws + 50331648);       // 33554432 bf16 [b][vox][128] -> 83886080
  float* Gcnt = (float*)(ws + 83886080);     // 524288   -> 84410368
  float* stats = (float*)(ws + 84410368);    // 4096     -> 84414464
  int*   pvox = (int*)(ws + 84414464);       // 262144   -> 84676608
  u16*   pf   = (u16*)(ws + 84676608);       // 16777216 -> 101453824
  u16*   Wh1  = (u16*)(ws + 101453824);      // 442368   -> 101896192
  u16*   Wl1  = (u16*)(ws + 101896192);      // 442368   -> 102338560
  u16*   Wh2  = (u16*)(ws + 102338560);      // 884736   -> 103223296
  u16*   Wl2  = (u16*)(ws + 103223296);      // 884736   -> 104108032
  u16*   Whm  = (u16*)(ws + 104108032);      // 16384    -> 104124416
  u16*   Wlm  = (u16*)(ws + 104124416);      // 16384    -> 104140800 (~104 MB)

  hipMemsetAsync(ws, 0, 33554432, stream);                   // Gsum
  hipMemsetAsync(ws + 83886080, 0, 524288 + 4096, stream);   // Gcnt + stats

  convert_weights<<<(27 * 128 * 128 + 255) / 256, 256, 0, stream>>>(
      conv1_w, conv2_w, mlp_w, Wh1, Wl1, Wh2, Wl2, Whm, Wlm);
  calc_pvox<<<(4 * NPTS + 255) / 256, 256, 0, stream>>>(coords, pvox);
  scatter_feats<<<16384, 256, 0, stream>>>(features, pvox, Gsum, Gcnt);
  finalize_grid<<<32768, 256, 0, stream>>>(Gsum, Gcnt, X1);
  conv_mfma16w<64><<<1024, 256, 0, stream>>>(
      X1, Wh1, Wl1, conv1_b, gn1_g, gn1_b, X2);
  mlp_mfma<<<1024, 256, 0, stream>>>(features, Whm, Wlm, mlp_b, pf, stats);
  conv_mfma16w<128><<<1024, 256, 0, stream>>>(
      X2, Wh2, Wl2, conv2_b, gn2_g, gn2_b, H);
  final_fuse<<<1024, 256, 0, stream>>>(coords, H, pf, stats, gnp_g, gnp_b,
                                       (float*)d_out);
}

// Round 5
// 647.532 us; speedup vs baseline: 2.0229x; 1.3566x over previous
//
#include <hip/hip_runtime.h>

typedef unsigned short u16;
typedef __attribute__((ext_vector_type(8))) short s16x8;
typedef __attribute__((ext_vector_type(4))) float f32x4;

#define R3 32768
#define NPTS 16384

__device__ __forceinline__ float b2f(u16 u) {
  union { unsigned int i; float f; } v; v.i = ((unsigned int)u) << 16; return v.f;
}
__device__ __forceinline__ u16 f2b(float f) {
  union { float f; unsigned int i; } v; v.f = f;
  unsigned int x = v.i;
  return (u16)((x + 0x7fffu + ((x >> 16) & 1u)) >> 16);
}
__device__ __forceinline__ void split2(float x, u16& h, u16& l) {
  h = f2b(x); l = f2b(x - b2f(h));
}
__device__ __forceinline__ float silu(float x) {
  return x / (1.f + __expf(-x));
}

// ---- K0: weights -> hi/lo bf16. conv: [tap][co][ci]; mlp: [co][ci] --------
__global__ void convert_weights(const float* __restrict__ w1, const float* __restrict__ w2,
                                const float* __restrict__ wm,
                                u16* __restrict__ Wh1, u16* __restrict__ Wl1,
                                u16* __restrict__ Wh2, u16* __restrict__ Wl2,
                                u16* __restrict__ Whm, u16* __restrict__ Wlm) {
  int e = blockIdx.x * 256 + threadIdx.x;
  if (e < 27 * 128 * 64) {
    int t = e / (128 * 64), co = (e / 64) % 128, ci = e % 64;
    split2(w1[(co * 64 + ci) * 27 + t], Wh1[e], Wl1[e]);
  }
  if (e < 27 * 128 * 128) {
    int t = e / (128 * 128), co = (e / 128) % 128, ci = e % 128;
    split2(w2[(co * 128 + ci) * 27 + t], Wh2[e], Wl2[e]);
  }
  if (e < 128 * 64) split2(wm[e], Whm[e], Wlm[e]);
}

// ---- K_pvox (proven) ------------------------------------------------------
__global__ void calc_pvox(const float* __restrict__ coords, int* __restrict__ pvox) {
  int t = blockIdx.x * 256 + threadIdx.x;  // < 4*16384
  if (t >= 4 * NPTS) return;
  const float* cp = coords + (size_t)t * 3;
  int ix = min(max((int)floorf(cp[0] * 32.f), 0), 31);
  int iy = min(max((int)floorf(cp[1] * 32.f), 0), 31);
  int iz = min(max((int)floorf(cp[2] * 32.f), 0), 31);
  pvox[t] = (ix * 32 + iy) * 32 + iz;
}

// ---- K_scatter: coalesced-atomic version ----------------------------------
// Old: lane = point index -> 64 lanes hit 64 random voxels = 64 cachelines
// per wave, each 4B atomic dragging a full line through HBM (Gsum > L2).
// New: stage [64ci x 64n] tile coalesced, transpose in LDS, then lane = ci:
// per point one 64-lane burst of CONSECUTIVE atomics (4 cachelines, 16x
// fewer line-transactions). Same atomic semantics, same sums.
__global__ void __launch_bounds__(256)
scatter_feats(const float* __restrict__ features, const int* __restrict__ pvox,
              float* __restrict__ Gsum, float* __restrict__ Gcnt) {
  __shared__ float trans[64][65];
  __shared__ int vox[64];
  const int tid = threadIdx.x;
  const int bi = blockIdx.x >> 8;          // 1024 blocks: 4 batches x 256 tiles
  const int n0 = (blockIdx.x & 255) << 6;
  if (tid < 64) vox[tid] = pvox[bi * NPTS + n0 + tid];
  for (int e = tid; e < 4096; e += 256) {
    int ci = e >> 6, nn = e & 63;          // lane varies nn -> coalesced read
    trans[nn][ci] = features[((size_t)bi * 64 + ci) * NPTS + n0 + nn];
  }
  __syncthreads();
  const int wave = tid >> 6, lane = tid & 63;
  for (int pi = 0; pi < 16; ++pi) {
    int nn = wave * 16 + pi;
    int v = vox[nn];
    atomicAdd(&Gsum[((size_t)bi * R3 + v) * 64 + lane], trans[nn][lane]);
    if (lane == 0) atomicAdd(&Gcnt[bi * R3 + v], 1.f);
  }
}

// ---- K_finalize: X1 = bf16(Gsum / max(cnt,1)), 4 ch/thread vectorized -----
__global__ void __launch_bounds__(256)
finalize_grid(const float* __restrict__ Gsum, const float* __restrict__ Gcnt,
              u16* __restrict__ X1) {
  size_t g = (size_t)blockIdx.x * 256 + threadIdx.x;  // < 4*32768*16
  float c = fmaxf(Gcnt[g >> 4], 1.f);
  float4 s = ((const float4*)Gsum)[g];
  unsigned h0 = f2b(s.x / c), h1 = f2b(s.y / c), h2 = f2b(s.z / c), h3 = f2b(s.w / c);
  uint2 o; o.x = h0 | (h1 << 16); o.y = h2 | (h3 << 16);
  *(uint2*)(X1 + g * 4) = o;
}

// ---- conv (EXACT r0-proven kernel, best measured 269 us) ------------------
// X bf16 [b][vox][CIN], W split hi/lo bf16 [tap][128co][ci]. 4 y-lines per
// block (128 output voxels). 2-term split MFMA, calibrated C/D decode
// (PROVEN r8/r9). Epilogue scratch aliases X LDS buffer.
template<int CIN>
__global__ void __launch_bounds__(256)
conv_mfma16(const u16* __restrict__ X, const u16* __restrict__ Wh, const u16* __restrict__ Wl,
            const float* __restrict__ bias, const float* __restrict__ gamma,
            const float* __restrict__ beta, u16* __restrict__ Yb) {
  constexpr int CINP = CIN + 8;            // row stride (odd x 16B)
  constexpr int ROWS = 136;                // 4 y-lines x 34 z-halo
  constexpr int KS = CIN / 32;
  constexpr int XBYTES = ROWS * CINP * 2;
  constexpr int SBYTES = 4 * 2 * 32 * 33 * 4;   // 4 waves x 2 lines x [32co][33z]
  __shared__ __align__(16) char ldsbuf[(XBYTES > SBYTES) ? XBYTES : SBYTES];
  u16* Xs = (u16*)ldsbuf;
  float* ldsW = (float*)ldsbuf;            // valid only after X reads drained

  const int tid = threadIdx.x;
  const int wave = tid >> 6, lane = tid & 63;
  const int l15 = lane & 15, q = lane >> 4;
  const int cobase = wave * 32;

  const int bi = blockIdx.x >> 8;
  const int rem = blockIdx.x & 255;
  const int x = rem >> 3, y0 = (rem & 7) << 2;

  // ---- runtime C/D calibration (PROVEN r8) ----
  u16 oneb = f2b(1.0f), lidb = f2b((float)(l15 + 1));
  s16x8 vone, vlid;
#pragma unroll
  for (int e = 0; e < 8; ++e) { vone[e] = (short)oneb; vlid[e] = (short)lidb; }
  f32x4 z4 = {0.f, 0.f, 0.f, 0.f};
  f32x4 d1 = __builtin_amdgcn_mfma_f32_16x16x32_bf16(vlid, vone, z4, 0, 0, 0);
  f32x4 d2 = __builtin_amdgcn_mfma_f32_16x16x32_bf16(vone, vlid, z4, 0, 0, 0);
  int mdec[4], ndec[4];
#pragma unroll
  for (int r = 0; r < 4; ++r) {
    mdec[r] = (int)(d1[r] * 0.03125f + 0.5f) - 1;
    ndec[r] = (int)(d2[r] * 0.03125f + 0.5f) - 1;
  }

  f32x4 acc[2][2][4];  // [ct][vt][line]
#pragma unroll
  for (int a = 0; a < 2; ++a)
#pragma unroll
    for (int b = 0; b < 2; ++b)
#pragma unroll
      for (int c = 0; c < 4; ++c) acc[a][b][c] = (f32x4){0.f, 0.f, 0.f, 0.f};

  constexpr int CH8 = CIN / 8;
  for (int g = 0; g < 9; ++g) {
    __syncthreads();
    const int dx = g / 3 - 1, dy = g % 3 - 1;
    const int xs = x + dx;
    for (int c = tid; c < ROWS * CH8; c += 256) {   // pure uint4 copy staging
      int rr = c / CH8, k = (c % CH8) * 8;
      uint4 val; val.x = val.y = val.z = val.w = 0u;
      int vy = rr / 34;                    // 0..3
      int zz = rr - vy * 34 - 1;           // z' in [-1,32]
      int ys = y0 + vy + dy;
      if (xs >= 0 && xs < 32 && ys >= 0 && ys < 32 && zz >= 0 && zz < 32)
        val = *(const uint4*)(X + ((size_t)bi * R3 + (size_t)((xs * 32 + ys) * 32 + zz)) * CIN + k);
      *(uint4*)(&Xs[rr * CINP + k]) = val;
    }
    __syncthreads();
    for (int dz = 0; dz < 3; ++dz) {
      const int t = g * 3 + dz;
#pragma unroll
      for (int kb = 0; kb < KS; ++kb) {
        const int ko = kb * 32 + q * 8;
        s16x8 ah[2], al[2], bb[2][4];
#pragma unroll
        for (int ct = 0; ct < 2; ++ct) {
          size_t wo = ((size_t)(t * 128 + cobase + ct * 16 + l15)) * CIN + ko;
          ah[ct] = *(const s16x8*)(Wh + wo);
          al[ct] = *(const s16x8*)(Wl + wo);
        }
#pragma unroll
        for (int vt = 0; vt < 2; ++vt)
#pragma unroll
          for (int ln = 0; ln < 4; ++ln)
            bb[vt][ln] = *(const s16x8*)(&Xs[(ln * 34 + vt * 16 + l15 + dz) * CINP + ko]);
#pragma unroll
        for (int ct = 0; ct < 2; ++ct)
#pragma unroll
          for (int vt = 0; vt < 2; ++vt)
#pragma unroll
            for (int ln = 0; ln < 4; ++ln) {
              acc[ct][vt][ln] = __builtin_amdgcn_mfma_f32_16x16x32_bf16(
                  ah[ct], bb[vt][ln], acc[ct][vt][ln], 0, 0, 0);
              acc[ct][vt][ln] = __builtin_amdgcn_mfma_f32_16x16x32_bf16(
                  al[ct], bb[vt][ln], acc[ct][vt][ln], 0, 0, 0);
            }
      }
    }
  }

  // ---- epilogue: decoded scatter through LDS, 2 lines per pass ------------
  const int half = lane >> 5, zl = lane & 31;
  for (int p = 0; p < 2; ++p) {
    __syncthreads();   // drains Xs reads -> safe to overwrite
#pragma unroll
    for (int l2 = 0; l2 < 2; ++l2)
#pragma unroll
      for (int ct = 0; ct < 2; ++ct)
#pragma unroll
        for (int vt = 0; vt < 2; ++vt)
#pragma unroll
          for (int r = 0; r < 4; ++r)
            ldsW[((wave * 2 + l2) * 32 + ct * 16 + mdec[r]) * 33 + vt * 16 + ndec[r]] =
                acc[ct][vt][2 * p + l2][r];
    __syncthreads();
    const int co0 = cobase + half * 16;
#pragma unroll
    for (int l2 = 0; l2 < 2; ++l2) {
      float v[16];
#pragma unroll
      for (int j = 0; j < 16; ++j)
        v[j] = ldsW[((wave * 2 + l2) * 32 + half * 16 + j) * 33 + zl] + bias[co0 + j];
      float mu = 0.f;
#pragma unroll
      for (int j = 0; j < 16; ++j) mu += v[j];
      mu *= 0.0625f;
      float var = 0.f;
#pragma unroll
      for (int j = 0; j < 16; ++j) { float d = v[j] - mu; var = fmaf(d, d, var); }
      var *= 0.0625f;
      float rs = rsqrtf(var + 1e-5f);
#pragma unroll
      for (int j = 0; j < 16; ++j) {
        float xn = (v[j] - mu) * rs * gamma[co0 + j] + beta[co0 + j];
        v[j] = silu(xn);
      }
      size_t row = (size_t)bi * R3 + (size_t)((x * 32 + y0 + 2 * p + l2) * 32 + zl);
      u16 outv[16];
#pragma unroll
      for (int j = 0; j < 16; ++j) outv[j] = f2b(v[j]);
      u16* yp = Yb + row * 128 + co0;
      *(uint4*)(yp)     = *(uint4*)(outv);
      *(uint4*)(yp + 8) = *(uint4*)(outv + 8);
    }
  }
}

// ---- K_mlp: MFMA 1x1 conv + fused global-GN stats -------------------------
__global__ void __launch_bounds__(256)
mlp_mfma(const float* __restrict__ features, const u16* __restrict__ Whm,
         const u16* __restrict__ Wlm, const float* __restrict__ mb,
         u16* __restrict__ pf, float* __restrict__ stats) {
  constexpr int XBYTES = 64 * 72 * 2;
  constexpr int SBYTES = 4 * 64 * 33 * 4;   // 4 waves x [64pt][32co+1]
  __shared__ __align__(16) char ldsbuf[(XBYTES > SBYTES) ? XBYTES : SBYTES];
  u16* Xs = (u16*)ldsbuf;
  float* ldsW = (float*)ldsbuf;

  const int tid = threadIdx.x;
  const int wave = tid >> 6, lane = tid & 63;
  const int l15 = lane & 15, q = lane >> 4;
  const int cobase = wave * 32;
  const int bi = blockIdx.x >> 8;
  const int n0 = (blockIdx.x & 255) << 6;

  // calibration (PROVEN r8)
  u16 oneb = f2b(1.0f), lidb = f2b((float)(l15 + 1));
  s16x8 vone, vlid;
#pragma unroll
  for (int e = 0; e < 8; ++e) { vone[e] = (short)oneb; vlid[e] = (short)lidb; }
  f32x4 z4 = {0.f, 0.f, 0.f, 0.f};
  f32x4 d1 = __builtin_amdgcn_mfma_f32_16x16x32_bf16(vlid, vone, z4, 0, 0, 0);
  f32x4 d2 = __builtin_amdgcn_mfma_f32_16x16x32_bf16(vone, vlid, z4, 0, 0, 0);
  int mdec[4], ndec[4];
#pragma unroll
  for (int r = 0; r < 4; ++r) {
    mdec[r] = (int)(d1[r] * 0.03125f + 0.5f) - 1;
    ndec[r] = (int)(d2[r] * 0.03125f + 0.5f) - 1;
  }

  // stage transpose: Xs[pt][ci]
  for (int e = tid; e < 4096; e += 256) {
    int ci = e >> 6, nn = e & 63;
    Xs[nn * 72 + ci] = f2b(features[((size_t)bi * 64 + ci) * NPTS + n0 + nn]);
  }
  __syncthreads();

  f32x4 acc[2][4];  // [ct][vt: 4 point-tiles of 16]
#pragma unroll
  for (int a = 0; a < 2; ++a)
#pragma unroll
    for (int b = 0; b < 4; ++b) acc[a][b] = (f32x4){0.f, 0.f, 0.f, 0.f};

#pragma unroll
  for (int kb = 0; kb < 2; ++kb) {
    const int ko = kb * 32 + q * 8;
    s16x8 ah[2], al[2], bb[4];
#pragma unroll
    for (int ct = 0; ct < 2; ++ct) {
      size_t wo = ((size_t)(cobase + ct * 16 + l15)) * 64 + ko;
      ah[ct] = *(const s16x8*)(Whm + wo);
      al[ct] = *(const s16x8*)(Wlm + wo);
    }
#pragma unroll
    for (int vt = 0; vt < 4; ++vt)
      bb[vt] = *(const s16x8*)(&Xs[(vt * 16 + l15) * 72 + ko]);
#pragma unroll
    for (int ct = 0; ct < 2; ++ct)
#pragma unroll
      for (int vt = 0; vt < 4; ++vt) {
        acc[ct][vt] = __builtin_amdgcn_mfma_f32_16x16x32_bf16(ah[ct], bb[vt], acc[ct][vt], 0, 0, 0);
        acc[ct][vt] = __builtin_amdgcn_mfma_f32_16x16x32_bf16(al[ct], bb[vt], acc[ct][vt], 0, 0, 0);
      }
  }

  // epilogue: decoded scatter -> ldsW[wave][pt][co32], then store + stats
  __syncthreads();
#pragma unroll
  for (int ct = 0; ct < 2; ++ct)
#pragma unroll
    for (int vt = 0; vt < 4; ++vt)
#pragma unroll
      for (int r = 0; r < 4; ++r)
        ldsW[(wave * 64 + vt * 16 + ndec[r]) * 33 + ct * 16 + mdec[r]] = acc[ct][vt][r];
  __syncthreads();

  float v[32];
  float s0 = 0.f, q0 = 0.f, s1 = 0.f, q1 = 0.f;
#pragma unroll
  for (int j = 0; j < 32; ++j) {
    v[j] = ldsW[(wave * 64 + lane) * 33 + j] + mb[cobase + j];
    if (j < 16) { s0 += v[j]; q0 = fmaf(v[j], v[j], q0); }
    else        { s1 += v[j]; q1 = fmaf(v[j], v[j], q1); }
  }
  u16 outv[32];
#pragma unroll
  for (int j = 0; j < 32; ++j) outv[j] = f2b(v[j]);
  u16* yp = pf + ((size_t)bi * NPTS + n0 + lane) * 128 + cobase;
#pragma unroll
  for (int k = 0; k < 4; ++k) *(uint4*)(yp + 8 * k) = *(uint4*)(outv + 8 * k);

#pragma unroll
  for (int off = 32; off > 0; off >>= 1) {
    s0 += __shfl_xor(s0, off); q0 += __shfl_xor(q0, off);
    s1 += __shfl_xor(s1, off); q1 += __shfl_xor(q1, off);
  }
  if (lane == 0) {
    atomicAdd(&stats[(bi * 8 + 2 * wave + 0) * 2 + 0], s0);
    atomicAdd(&stats[(bi * 8 + 2 * wave + 0) * 2 + 1], q0);
    atomicAdd(&stats[(bi * 8 + 2 * wave + 1) * 2 + 0], s1);
    atomicAdd(&stats[(bi * 8 + 2 * wave + 1) * 2 + 1], q1);
  }
}

// ---- K_final (proven) -----------------------------------------------------
__global__ void __launch_bounds__(256)
final_fuse(const float* __restrict__ coords, const u16* __restrict__ H,
           const u16* __restrict__ pf, const float* __restrict__ stats,
           const float* __restrict__ gg, const float* __restrict__ gb,
           float* __restrict__ out) {
  __shared__ float trans[64][130];
  const int tid = threadIdx.x;
  const int wave = tid >> 6, lane = tid & 63;
  const int bi = blockIdx.x >> 8;
  const int p0 = (blockIdx.x & 255) << 6;
  const int co = lane * 2;
  const int grp = co >> 4;
  const float cntInv = 1.f / (16.f * 16384.f);
  float S  = stats[(bi * 8 + grp) * 2 + 0];
  float SS = stats[(bi * 8 + grp) * 2 + 1];
  float mu = S * cntInv;
  float var = SS * cntInv - mu * mu;
  float rs = rsqrtf(var + 1e-5f);
  float g0 = gg[co], g1 = gg[co + 1], b0 = gb[co], b1 = gb[co + 1];

  for (int pi = 0; pi < 16; ++pi) {
    int pl = wave * 16 + pi;
    int p = p0 + pl;
    const float* cp = coords + ((size_t)bi * NPTS + p) * 3;
    float cx = cp[0] * 32.f, cy = cp[1] * 32.f, cz = cp[2] * 32.f;
    float fx = floorf(cx), fy = floorf(cy), fz = floorf(cz);
    int ix = min(max((int)fx, 0), 31);
    int iy = min(max((int)fy, 0), 31);
    int iz = min(max((int)fz, 0), 31);
    float rx = cx - fx, ry = cy - fy, rz = cz - fz;
    int hx = min(ix + 1, 31), hy = min(iy + 1, 31), hz = min(iz + 1, 31);
    float a0 = 0.f, a1 = 0.f;
#pragma unroll
    for (int k = 0; k < 8; ++k) {
      int xb = k >> 2, yb = (k >> 1) & 1, zb = k & 1;
      float w = (xb ? rx : 1.f - rx) * (yb ? ry : 1.f - ry) * (zb ? rz : 1.f - rz);
      int vi = ((xb ? hx : ix) * 32 + (yb ? hy : iy)) * 32 + (zb ? hz : iz);
      unsigned hv = *(const unsigned*)(H + ((size_t)bi * R3 + vi) * 128 + co);
      a0 += w * b2f((u16)(hv & 0xffff));
      a1 += w * b2f((u16)(hv >> 16));
    }
    unsigned pv = *(const unsigned*)(pf + ((size_t)bi * NPTS + p) * 128 + co);
    float q0 = (b2f((u16)(pv & 0xffff)) - mu) * rs * g0 + b0;
    float q1 = (b2f((u16)(pv >> 16)) - mu) * rs * g1 + b1;
    trans[pl][co]     = silu(q0) + a0;
    trans[pl][co + 1] = silu(q1) + a1;
  }
  __syncthreads();
  for (int e = tid; e < 8192; e += 256) {
    int c = e >> 6, pp = e & 63;
    out[((size_t)bi * 128 + c) * NPTS + p0 + pp] = trans[pp][c];
  }
}

// ---- host -----------------------------------------------------------------
extern "C" void kernel_launch(void* const* d_in, const int* in_sizes, int n_in,
                              void* d_out, int out_size, void* d_ws, size_t ws_size,
                              hipStream_t stream) {
  const float* coords   = (const float*)d_in[0];
  const float* features = (const float*)d_in[1];
  const float* conv1_w  = (const float*)d_in[2];
  const float* conv1_b  = (const float*)d_in[3];
  const float* gn1_g    = (const float*)d_in[4];
  const float* gn1_b    = (const float*)d_in[5];
  const float* conv2_w  = (const float*)d_in[6];
  const float* conv2_b  = (const float*)d_in[7];
  const float* gn2_g    = (const float*)d_in[8];
  const float* gn2_b    = (const float*)d_in[9];
  const float* mlp_w    = (const float*)d_in[10];
  const float* mlp_b    = (const float*)d_in[11];
  const float* gnp_g    = (const float*)d_in[12];
  const float* gnp_b    = (const float*)d_in[13];

  char* ws = (char*)d_ws;
  // layout (bytes) -- r0-proven compact layout (~104 MB):
  float* Gsum = (float*)(ws + 0);            // 33554432 fp32 [b][vox][64]; H bf16 aliases after conv1
  u16*   H    = (u16*)(ws + 0);              // 33554432 bf16 [b][vox][128]
  u16*   X1   = (u16*)(ws + 33554432);       // 16777216 bf16 [b][vox][64]  -> 50331648
  u16*   X2   = (u16*)(ws + 50331648);       // 33554432 bf16 [b][vox][128] -> 83886080
  float* Gcnt = (float*)(ws + 83886080);     // 524288   -> 84410368
  float* stats = (float*)(ws + 84410368);    // 4096     -> 84414464
  int*   pvox = (int*)(ws + 84414464);       // 262144   -> 84676608
  u16*   pf   = (u16*)(ws + 84676608);       // 16777216 -> 101453824
  u16*   Wh1  = (u16*)(ws + 101453824);      // 442368   -> 101896192
  u16*   Wl1  = (u16*)(ws + 101896192);      // 442368   -> 102338560
  u16*   Wh2  = (u16*)(ws + 102338560);      // 884736   -> 103223296
  u16*   Wl2  = (u16*)(ws + 103223296);      // 884736   -> 104108032
  u16*   Whm  = (u16*)(ws + 104108032);      // 16384    -> 104124416
  u16*   Wlm  = (u16*)(ws + 104124416);      // 16384    -> 104140800 (~104 MB)

  hipMemsetAsync(ws, 0, 33554432, stream);                   // Gsum
  hipMemsetAsync(ws + 83886080, 0, 524288 + 4096, stream);   // Gcnt + stats

  convert_weights<<<(27 * 128 * 128 + 255) / 256, 256, 0, stream>>>(
      conv1_w, conv2_w, mlp_w, Wh1, Wl1, Wh2, Wl2, Whm, Wlm);
  calc_pvox<<<(4 * NPTS + 255) / 256, 256, 0, stream>>>(coords, pvox);
  scatter_feats<<<1024, 256, 0, stream>>>(features, pvox, Gsum, Gcnt);
  finalize_grid<<<8192, 256, 0, stream>>>(Gsum, Gcnt, X1);
  conv_mfma16<64><<<1024, 256, 0, stream>>>(
      X1, Wh1, Wl1, conv1_b, gn1_g, gn1_b, X2);
  mlp_mfma<<<1024, 256, 0, stream>>>(features, Whm, Wlm, mlp_b, pf, stats);
  conv_mfma16<128><<<1024, 256, 0, stream>>>(
      X2, Wh2, Wl2, conv2_b, gn2_g, gn2_b, H);
  final_fuse<<<1024, 256, 0, stream>>>(coords, H, pf, stats, gnp_g, gnp_b,
                                       (float*)d_out);
}